// Round 5
// baseline (316.206 us; speedup 1.0000x reference)
//
#include <hip/hip_runtime.h>
#include <hip/hip_bf16.h>
#include <cstdint>
#include <cstddef>

// B=2, S=2048, D=1024, H=16, HD=64.  softmax over HEAD axis.
// v12: v11 + attn8 occupancy fix: single-buffered V LDS (68KB->50KB => 3
//   blocks/CU = 24 waves, was 2/16) at the cost of one extra barrier per
//   iter guarding the V overwrite. VGPR stays ~64 (bounds (512,6), cap 85;
//   v11 fit in 64 so no spill). s_setprio(1) around the compute cluster
//   (T5, +4-7% proven on attn with role-diverse resident blocks).
//   K double-buffer + slot-swizzle unchanged. den8/qkv/gemm_out2 unchanged.

typedef __bf16 bf16x8 __attribute__((ext_vector_type(8)));
typedef __bf16 bf16x4 __attribute__((ext_vector_type(4)));
typedef _Float16 f16x2 __attribute__((ext_vector_type(2)));
typedef _Float16 f16x4 __attribute__((ext_vector_type(4)));
typedef _Float16 f16x8 __attribute__((ext_vector_type(8)));
typedef float floatx4 __attribute__((ext_vector_type(4)));

#define S_LEN 2048
#define DIM 1024
#define NH 16
#define HD 64
#define MTOT 4096  // B * S
#define C_EXP 0.1803368801111244f  // log2(e)/8

__device__ __forceinline__ float fast_exp2(float x) { return __builtin_amdgcn_exp2f(x); }

__device__ __forceinline__ f16x2 pk_cvt(float a, float b) {
    return __builtin_bit_cast(f16x2, __builtin_amdgcn_cvt_pkrtz(a, b));
}

__device__ __forceinline__ void g2l16(const void* g, void* l) {
    __builtin_amdgcn_global_load_lds(
        (const __attribute__((address_space(1))) void*)g,
        (__attribute__((address_space(3))) void*)l, 16, 0, 0);
}

// ---------------- fused cast: x -> bf16, Wq/Wk/Wv -> bf16, Wo -> f16 ----------------
__global__ void cast_all(const float* __restrict__ x,
                         const float* __restrict__ w0, const float* __restrict__ w1,
                         const float* __restrict__ w2, const float* __restrict__ w3,
                         __bf16* __restrict__ xb,
                         __bf16* __restrict__ o0, __bf16* __restrict__ o1,
                         __bf16* __restrict__ o2, _Float16* __restrict__ o3) {
    int bid = blockIdx.x;
    if (bid < 4096) {
        int i = (bid * 256 + threadIdx.x) * 4;
        float4 v = *(const float4*)&x[i];
        bf16x4 o;
        o.x = (__bf16)v.x; o.y = (__bf16)v.y; o.z = (__bf16)v.z; o.w = (__bf16)v.w;
        *(bf16x4*)&xb[i] = o;
        return;
    }
    bid -= 4096;
    int wi = bid >> 10;
    int i = ((bid & 1023) * 256 + threadIdx.x) * 4;
    if (wi == 3) {
        float4 v = *(const float4*)&w3[i];
        f16x4 o;
        o[0] = (_Float16)v.x; o[1] = (_Float16)v.y; o[2] = (_Float16)v.z; o[3] = (_Float16)v.w;
        *(f16x4*)&o3[i] = o;
        return;
    }
    const float* s = (wi == 0) ? w0 : (wi == 1) ? w1 : w2;
    __bf16* d = (wi == 0) ? o0 : (wi == 1) ? o1 : o2;
    float4 v = *(const float4*)&s[i];
    bf16x4 o;
    o.x = (__bf16)v.x; o.y = (__bf16)v.y; o.z = (__bf16)v.z; o.w = (__bf16)v.w;
    *(bf16x4*)&d[i] = o;
}

// ---------------- fused QKV projection GEMM (m97 structure) ----------------
__global__ __launch_bounds__(256, 2) void qkv_gemm(const __bf16* __restrict__ A,
                                                   const __bf16* __restrict__ Wq,
                                                   const __bf16* __restrict__ Wk,
                                                   const __bf16* __restrict__ Wv,
                                                   const float* __restrict__ bq,
                                                   const float* __restrict__ bk,
                                                   const float* __restrict__ bv,
                                                   __bf16* __restrict__ Qo,
                                                   __bf16* __restrict__ Ko,
                                                   _Float16* __restrict__ Vt) {
    const int tng = blockIdx.x * 128, tm = blockIdx.y * 128;
    const int wsel = tng >> 10, tn = tng & 1023;
    const __bf16* W = (wsel == 0) ? Wq : (wsel == 1) ? Wk : Wv;
    const float* bias = (wsel == 0) ? bq : (wsel == 1) ? bk : bv;
    __shared__ __bf16 As[128 * 32];
    __shared__ __bf16 Bs[128 * 32];
    const int tid = threadIdx.x, wid = tid >> 6, lane = tid & 63;
    const int l15 = lane & 15, quad = lane >> 4;
    const int wm = (wid >> 1) * 64, wn = (wid & 1) * 64;
    floatx4 acc[4][4] = {};
    for (int k0 = 0; k0 < DIM; k0 += 32) {
        __syncthreads();
#pragma unroll
        for (int i = 0; i < 2; ++i) {
            int slot = i * 256 + tid;
            int r = slot >> 2, c8 = (slot & 3) * 8;
            g2l16(&A[(size_t)(tm + r) * DIM + k0 + c8], &As[slot * 8]);
            g2l16(&W[(size_t)(tn + r) * DIM + k0 + c8], &Bs[slot * 8]);
        }
        __syncthreads();
        bf16x8 af[4], bf[4];
#pragma unroll
        for (int t = 0; t < 4; ++t) {
            af[t] = *(const bf16x8*)&As[(wm + t * 16 + l15) * 32 + quad * 8];
            bf[t] = *(const bf16x8*)&Bs[(wn + t * 16 + l15) * 32 + quad * 8];
        }
#pragma unroll
        for (int im = 0; im < 4; ++im)
#pragma unroll
            for (int in = 0; in < 4; ++in)
                acc[im][in] = __builtin_amdgcn_mfma_f32_16x16x32_bf16(af[im], bf[in], acc[im][in], 0, 0, 0);
    }
    if (wsel < 2) {
        __bf16* O = wsel ? Ko : Qo;
#pragma unroll
        for (int im = 0; im < 4; ++im)
#pragma unroll
            for (int in = 0; in < 4; ++in)
#pragma unroll
                for (int r = 0; r < 4; ++r) {
                    int row = tm + wm + im * 16 + quad * 4 + r;
                    int col = tn + wn + in * 16 + l15;
                    O[(size_t)row * DIM + col] = (__bf16)(acc[im][in][r] + bias[col]);
                }
    } else {
#pragma unroll
        for (int im = 0; im < 4; ++im)
#pragma unroll
            for (int in = 0; in < 4; ++in) {
                int cv = tn + wn + in * 16 + l15;
                int row4 = tm + wm + im * 16 + quad * 4;
                float bv_ = bias[cv];
                f16x4 o;
#pragma unroll
                for (int r = 0; r < 4; ++r) o[r] = (_Float16)(acc[im][in][r] + bv_);
                *(f16x4*)&Vt[(size_t)cv * MTOT + row4] = o;
            }
    }
}

// ---------------- pass 1: rd = 1/sum_h exp(s/8)  (f16 out), 8-wave blocks ----------------
// (v9 form exactly: per-mp fragment reads, bounds (512,8), K slot-swizzle)
__global__ __launch_bounds__(512, 8) void den8(const __bf16* __restrict__ Q,
                                               const __bf16* __restrict__ Km,
                                               _Float16* __restrict__ rd) {
    const int kt = blockIdx.x * 64, qt = blockIdx.y * 128, b = blockIdx.z;
    __shared__ __bf16 Ks[2][2 * 2 * 64 * 32];  // 2 bufs x 16 KB
    const int tid = threadIdx.x, wid = tid >> 6, lane = tid & 63;
    const int l15 = lane & 15, quad = lane >> 4;
    const int kswz = ((lane >> 1) & 3) << 3;  // element offset XOR for reads
    const int wq = wid * 16;
    floatx4 dsum[4] = {};
    const size_t qrow = (size_t)(b * S_LEN + qt + wq + l15) * DIM;
    const size_t kbase = (size_t)(b * S_LEN + kt) * DIM;

#pragma unroll
    for (int i = 0; i < 2; ++i) {
        int slot = i * 512 + tid;
        int hs = slot >> 9, rem = slot & 511;
        int p = rem >> 8, rem2 = rem & 255;
        int r = rem2 >> 2;
        int c8 = (((rem2 & 3) ^ ((rem2 >> 3) & 3)) * 8);  // pre-swizzled global slot
        g2l16(&Km[kbase + (size_t)r * DIM + hs * HD + p * 32 + c8], &Ks[0][slot * 8]);
    }
    for (int hh = 0; hh < 8; ++hh) {
        const int cur = hh & 1, nxt = cur ^ 1;
        __syncthreads();
        bf16x8 af[2][2];
#pragma unroll
        for (int hs = 0; hs < 2; ++hs) {
            af[hs][0] = *(const bf16x8*)&Q[qrow + (hh * 2 + hs) * HD + quad * 8];
            af[hs][1] = *(const bf16x8*)&Q[qrow + (hh * 2 + hs) * HD + 32 + quad * 8];
        }
        if (hh + 1 < 8) {
#pragma unroll
            for (int i = 0; i < 2; ++i) {
                int slot = i * 512 + tid;
                int hs = slot >> 9, rem = slot & 511;
                int p = rem >> 8, rem2 = rem & 255;
                int r = rem2 >> 2;
                int c8 = (((rem2 & 3) ^ ((rem2 >> 3) & 3)) * 8);
                g2l16(&Km[kbase + (size_t)r * DIM + ((hh + 1) * 2 + hs) * HD + p * 32 + c8],
                      &Ks[nxt][slot * 8]);
            }
        }
#pragma unroll
        for (int hs = 0; hs < 2; ++hs) {
#pragma unroll
            for (int n = 0; n < 4; ++n) {
                bf16x8 b0 = *(const bf16x8*)&Ks[cur][hs * 4096 + (n * 16 + l15) * 32 + ((quad * 8) ^ kswz)];
                bf16x8 b1 = *(const bf16x8*)&Ks[cur][hs * 4096 + 2048 + (n * 16 + l15) * 32 + ((quad * 8) ^ kswz)];
                floatx4 acc = {};
                acc = __builtin_amdgcn_mfma_f32_16x16x32_bf16(af[hs][0], b0, acc, 0, 0, 0);
                acc = __builtin_amdgcn_mfma_f32_16x16x32_bf16(af[hs][1], b1, acc, 0, 0, 0);
                floatx4 sc = acc * C_EXP;
                floatx4 e;
#pragma unroll
                for (int r = 0; r < 4; ++r) e[r] = fast_exp2(sc[r]);
                dsum[n] += e;
            }
        }
    }
#pragma unroll
    for (int n = 0; n < 4; ++n)
#pragma unroll
        for (int r = 0; r < 4; ++r) {
            int q = qt + wq + quad * 4 + r;
            int k = kt + n * 16 + l15;
            rd[(size_t)(b * S_LEN + q) * S_LEN + k] = (_Float16)(1.0f / dsum[n][r]);
        }
}

// ---------------- pass 2: partial AO, TWO heads per block, single-buffered V ----------------
__global__ __launch_bounds__(512, 6) void attn8(const __bf16* __restrict__ Q,
                                                const __bf16* __restrict__ Km,
                                                const _Float16* __restrict__ Vt,
                                                const _Float16* __restrict__ rd,
                                                _Float16* __restrict__ AO1,
                                                _Float16* __restrict__ AO2) {
    const int qt = (blockIdx.x >> 1) * 128, ks = blockIdx.x & 1;
    const int h0 = blockIdx.y * 2, b = blockIdx.z;  // heads h0, h0+1
    __shared__ __bf16 Ks[2][2 * 2 * 64 * 32];   // [buf][head][panel][tok][32], 16KB/buf (swizzled)
    __shared__ _Float16 Vts[2 * 64 * 72];       // SINGLE buf: [head][d][tok+pad], 18KB
    const int tid = threadIdx.x, wid = tid >> 6, lane = tid & 63;
    const int l15 = lane & 15, quad = lane >> 4;
    const int kswz = ((lane >> 1) & 3) << 3;  // element offset XOR for reads
    const int wq = wid * 16;
    const size_t qrow = (size_t)(b * S_LEN + qt + wq + l15) * DIM + h0 * HD;
    bf16x8 qf[2][2];
    qf[0][0] = *(const bf16x8*)&Q[qrow + quad * 8];
    qf[0][1] = *(const bf16x8*)&Q[qrow + 32 + quad * 8];
    qf[1][0] = *(const bf16x8*)&Q[qrow + HD + quad * 8];
    qf[1][1] = *(const bf16x8*)&Q[qrow + HD + 32 + quad * 8];
    const _Float16* rdrow = &rd[(size_t)(b * S_LEN + qt + wq + l15) * S_LEN];
    floatx4 oacc[2][4] = {};
    const int kt0 = ks * (S_LEN / 2);
    const size_t kdim = (size_t)b * S_LEN * DIM;
    const int vr = tid >> 3, vc = (tid & 7) * 8;

    // K staging indices (2 head panels, 1024 slots of 16B, 2 per thread)
#define STAGE_K(BUF, KT_)                                                            \
    {                                                                                \
        _Pragma("unroll")                                                            \
        for (int i = 0; i < 2; ++i) {                                                \
            int slot = i * 512 + tid;                                                \
            int hh = slot >> 9, rem = slot & 511;                                    \
            int p = rem >> 8, rem2 = rem & 255;                                      \
            int r = rem2 >> 2;                                                       \
            int c8 = (((rem2 & 3) ^ ((rem2 >> 3) & 3)) * 8);                         \
            g2l16(&Km[kdim + (size_t)((KT_) + r) * DIM + (h0 + hh) * HD + p * 32 + c8], \
                  &Ks[BUF][slot * 8]);                                               \
        }                                                                            \
    }

    // prologue: stage kt0 into K buf 0 and V (single buf)
    {
        f16x8 v0 = *(const f16x8*)&Vt[(size_t)(h0 * HD + vr) * MTOT + b * S_LEN + kt0 + vc];
        f16x8 v1 = *(const f16x8*)&Vt[(size_t)((h0 + 1) * HD + vr) * MTOT + b * S_LEN + kt0 + vc];
        STAGE_K(0, kt0);
        *(f16x8*)&Vts[vr * 72 + vc] = v0;
        *(f16x8*)&Vts[4608 + vr * 72 + vc] = v1;
    }
    for (int it = 0; it < 16; ++it) {
        const int cur = it & 1, nxt = cur ^ 1;
        const int kt = kt0 + it * 64;
        __syncthreads();  // B1: K(it) g2l drained by issuers, V(it) commits visible
        // rv for this iter -- SHARED by both heads (denominator is per (q,k))
        f16x4 rv[4];
#pragma unroll
        for (int mp = 0; mp < 4; ++mp)
            rv[mp] = *(const f16x4*)&rdrow[kt + mp * 16 + quad * 4];
        // issue next tile's loads (V kept in regs; committed after B2)
        f16x8 vt0, vt1;
        const bool has_next = (it + 1 < 16);
        if (has_next) {
            const int ktn = kt + 64;
            vt0 = *(const f16x8*)&Vt[(size_t)(h0 * HD + vr) * MTOT + b * S_LEN + ktn + vc];
            vt1 = *(const f16x8*)&Vt[(size_t)((h0 + 1) * HD + vr) * MTOT + b * S_LEN + ktn + vc];
            STAGE_K(nxt, ktn);
        }
        // compute current tile, both heads
        __builtin_amdgcn_s_setprio(1);
#pragma unroll
        for (int mp = 0; mp < 4; ++mp) {
            const int krow = (mp * 16 + l15) * 32 + ((quad * 8) ^ kswz);
            f16x4 pa[2];
#pragma unroll
            for (int hh = 0; hh < 2; ++hh) {
                bf16x8 kf0 = *(const bf16x8*)&Ks[cur][hh * 4096 + krow];
                bf16x8 kf1 = *(const bf16x8*)&Ks[cur][hh * 4096 + 2048 + krow];
                floatx4 s = {};
                s = __builtin_amdgcn_mfma_f32_16x16x32_bf16(kf0, qf[hh][0], s, 0, 0, 0);
                s = __builtin_amdgcn_mfma_f32_16x16x32_bf16(kf1, qf[hh][1], s, 0, 0, 0);
                floatx4 sc = s * C_EXP;
                f16x2 p01 = pk_cvt(fast_exp2(sc[0]), fast_exp2(sc[1]));
                f16x2 p23 = pk_cvt(fast_exp2(sc[2]), fast_exp2(sc[3]));
                f16x4 p = __builtin_shufflevector(p01, p23, 0, 1, 2, 3);
                pa[hh] = p * rv[mp];  // v_pk_mul_f16 x2
            }
#pragma unroll
            for (int hh = 0; hh < 2; ++hh)
#pragma unroll
                for (int n = 0; n < 4; ++n) {
                    f16x4 vb = *(const f16x4*)&Vts[hh * 4608 + (n * 16 + l15) * 72 + mp * 16 + quad * 4];
                    oacc[hh][n] = __builtin_amdgcn_mfma_f32_16x16x16f16(pa[hh], vb, oacc[hh][n], 0, 0, 0);
                }
        }
        __builtin_amdgcn_s_setprio(0);
        // B2 + commit: all waves done reading V(it); overwrite with V(it+1)
        if (has_next) {
            __syncthreads();
            *(f16x8*)&Vts[vr * 72 + vc] = vt0;
            *(f16x8*)&Vts[4608 + vr * 72 + vc] = vt1;
        }
    }
#undef STAGE_K
    _Float16* AO = ks ? AO2 : AO1;
#pragma unroll
    for (int hh = 0; hh < 2; ++hh)
#pragma unroll
        for (int n = 0; n < 4; ++n)
#pragma unroll
            for (int r = 0; r < 4; ++r) {
                int row = qt + wq + quad * 4 + r;
                int col = (h0 + hh) * HD + n * 16 + l15;
                AO[(size_t)(b * S_LEN + row) * DIM + col] = (_Float16)oacc[hh][n][r];
            }
}

// ---------------- output projection: C = (AO1+AO2) @ Wo^T + bo ----------------
__global__ __launch_bounds__(256, 2) void gemm_out2(const _Float16* __restrict__ A1,
                                                    const _Float16* __restrict__ A2,
                                                    const _Float16* __restrict__ Bw,
                                                    const float* __restrict__ bias,
                                                    float* __restrict__ C) {
    const int tm = blockIdx.y * 128, tn = blockIdx.x * 64;
    __shared__ _Float16 As1[2 * 128 * 32];
    __shared__ _Float16 As2[2 * 128 * 32];
    __shared__ _Float16 Bs[2 * 64 * 32];
    const int tid = threadIdx.x, wid = tid >> 6, lane = tid & 63;
    const int l15 = lane & 15, quad = lane >> 4;
    const int wm = (wid >> 1) * 64, wn = (wid & 1) * 32;
    floatx4 acc[4][2] = {};
    for (int k0 = 0; k0 < DIM; k0 += 64) {
        __syncthreads();
#pragma unroll
        for (int i = 0; i < 4; ++i) {
            int slot = i * 256 + tid;
            int p = slot >> 9, rem = slot & 511;
            int r = rem >> 2, c8 = (rem & 3) * 8;
            size_t ga = (size_t)(tm + r) * DIM + k0 + p * 32 + c8;
            g2l16(&A1[ga], &As1[slot * 8]);
            g2l16(&A2[ga], &As2[slot * 8]);
        }
#pragma unroll
        for (int i = 0; i < 2; ++i) {
            int slot = i * 256 + tid;
            int p = slot >> 8, rem = slot & 255;
            int r = rem >> 2, c8 = (rem & 3) * 8;
            g2l16(&Bw[(size_t)(tn + r) * DIM + k0 + p * 32 + c8], &Bs[slot * 8]);
        }
        __syncthreads();
#pragma unroll
        for (int kc = 0; kc < 2; ++kc) {
            f16x8 af[4], bf[2];
#pragma unroll
            for (int t = 0; t < 4; ++t) {
                int off = kc * 4096 + (wm + t * 16 + l15) * 32 + quad * 8;
                f16x8 a1 = *(const f16x8*)&As1[off];
                f16x8 a2 = *(const f16x8*)&As2[off];
                af[t] = a1 + a2;
            }
#pragma unroll
            for (int t = 0; t < 2; ++t)
                bf[t] = *(const f16x8*)&Bs[kc * 2048 + (wn + t * 16 + l15) * 32 + quad * 8];
#pragma unroll
            for (int im = 0; im < 4; ++im)
#pragma unroll
                for (int in = 0; in < 2; ++in)
                    acc[im][in] = __builtin_amdgcn_mfma_f32_16x16x32_f16(af[im], bf[in], acc[im][in], 0, 0, 0);
        }
    }
#pragma unroll
    for (int im = 0; im < 4; ++im)
#pragma unroll
        for (int in = 0; in < 2; ++in)
#pragma unroll
            for (int r = 0; r < 4; ++r) {
                int row = tm + wm + im * 16 + quad * 4 + r;
                int col = tn + wn + in * 16 + l15;
                C[(size_t)row * DIM + col] = acc[im][in][r] + bias[col];
            }
}

extern "C" void kernel_launch(void* const* d_in, const int* in_sizes, int n_in,
                              void* d_out, int out_size, void* d_ws, size_t ws_size,
                              hipStream_t stream) {
    const float* x  = (const float*)d_in[0];
    const float* Wq = (const float*)d_in[1];
    const float* bq = (const float*)d_in[2];
    const float* Wk = (const float*)d_in[3];
    const float* bk = (const float*)d_in[4];
    const float* Wv = (const float*)d_in[5];
    const float* bv = (const float*)d_in[6];
    const float* Wo = (const float*)d_in[7];
    const float* bo = (const float*)d_in[8];
    float* out = (float*)d_out;

    char* ws = (char*)d_ws;
    const size_t MB = 1u << 20;
    __bf16*    xb  = (__bf16*)(ws);              // 8 MB
    __bf16*    Wqb = (__bf16*)(ws + 8 * MB);
    __bf16*    Wkb = (__bf16*)(ws + 10 * MB);
    __bf16*    Wvb = (__bf16*)(ws + 12 * MB);
    _Float16*  Wof = (_Float16*)(ws + 14 * MB);
    __bf16*    Qb  = (__bf16*)(ws + 16 * MB);    // 8 MB
    __bf16*    Kb  = (__bf16*)(ws + 24 * MB);    // 8 MB
    _Float16*  VtH = (_Float16*)(ws + 32 * MB);  // 8 MB
    _Float16*  rd  = (_Float16*)(ws + 40 * MB);  // 8 MB (f16)
    _Float16*  AO1 = (_Float16*)(ws + 56 * MB);  // 8 MB
    _Float16*  AO2 = (_Float16*)(ws + 64 * MB);  // 8 MB

    cast_all<<<8192, 256, 0, stream>>>(x, Wq, Wk, Wv, Wo, xb, Wqb, Wkb, Wvb, Wof);

    qkv_gemm<<<dim3(24, 32), 256, 0, stream>>>(xb, Wqb, Wkb, Wvb, bq, bk, bv, Qb, Kb, VtH);

    den8<<<dim3(S_LEN / 64, S_LEN / 128, 2), 512, 0, stream>>>(Qb, Kb, rd);

    attn8<<<dim3((S_LEN / 128) * 2, NH / 2, 2), 512, 0, stream>>>(Qb, Kb, VtH, rd, AO1, AO2);

    gemm_out2<<<dim3(DIM / 64, MTOT / 128), 256, 0, stream>>>(AO1, AO2, Wof, bo, out);
}

// Round 7
// 280.438 us; speedup vs baseline: 1.1275x; 1.1275x over previous
//
#include <hip/hip_runtime.h>
#include <hip/hip_bf16.h>
#include <cstdint>
#include <cstddef>

// B=2, S=2048, D=1024, H=16, HD=64.  softmax over HEAD axis.
// v14: v13's 4-way K-split occupancy theory, with v13's fatal bug fixed:
//   rd is 16MB (40..56MB), NOT 8MB -- v13 put AO4 at 48MB inside rd ->
//   attn8 clobbered rd while other blocks read it (absmax 1.3e4).
//   AO4 now lives at ws+72..80MB; host branches on ws_size: if >=80MB run
//   the 4-way path (1024 blocks = 4/CU, 50KB LDS -> 3 resident = 24 waves),
//   else fall back to the byte-identical v11 2-way path (known 71.5us).
//   AO3 reuses xb (dead after qkv_gemm). den8/qkv/cast unchanged.

typedef __bf16 bf16x8 __attribute__((ext_vector_type(8)));
typedef __bf16 bf16x4 __attribute__((ext_vector_type(4)));
typedef _Float16 f16x2 __attribute__((ext_vector_type(2)));
typedef _Float16 f16x4 __attribute__((ext_vector_type(4)));
typedef _Float16 f16x8 __attribute__((ext_vector_type(8)));
typedef float floatx4 __attribute__((ext_vector_type(4)));

#define S_LEN 2048
#define DIM 1024
#define NH 16
#define HD 64
#define MTOT 4096  // B * S
#define C_EXP 0.1803368801111244f  // log2(e)/8

__device__ __forceinline__ float fast_exp2(float x) { return __builtin_amdgcn_exp2f(x); }

__device__ __forceinline__ f16x2 pk_cvt(float a, float b) {
    return __builtin_bit_cast(f16x2, __builtin_amdgcn_cvt_pkrtz(a, b));
}

__device__ __forceinline__ void g2l16(const void* g, void* l) {
    __builtin_amdgcn_global_load_lds(
        (const __attribute__((address_space(1))) void*)g,
        (__attribute__((address_space(3))) void*)l, 16, 0, 0);
}

// ---------------- fused cast: x -> bf16, Wq/Wk/Wv -> bf16, Wo -> f16 ----------------
__global__ void cast_all(const float* __restrict__ x,
                         const float* __restrict__ w0, const float* __restrict__ w1,
                         const float* __restrict__ w2, const float* __restrict__ w3,
                         __bf16* __restrict__ xb,
                         __bf16* __restrict__ o0, __bf16* __restrict__ o1,
                         __bf16* __restrict__ o2, _Float16* __restrict__ o3) {
    int bid = blockIdx.x;
    if (bid < 4096) {
        int i = (bid * 256 + threadIdx.x) * 4;
        float4 v = *(const float4*)&x[i];
        bf16x4 o;
        o.x = (__bf16)v.x; o.y = (__bf16)v.y; o.z = (__bf16)v.z; o.w = (__bf16)v.w;
        *(bf16x4*)&xb[i] = o;
        return;
    }
    bid -= 4096;
    int wi = bid >> 10;
    int i = ((bid & 1023) * 256 + threadIdx.x) * 4;
    if (wi == 3) {
        float4 v = *(const float4*)&w3[i];
        f16x4 o;
        o[0] = (_Float16)v.x; o[1] = (_Float16)v.y; o[2] = (_Float16)v.z; o[3] = (_Float16)v.w;
        *(f16x4*)&o3[i] = o;
        return;
    }
    const float* s = (wi == 0) ? w0 : (wi == 1) ? w1 : w2;
    __bf16* d = (wi == 0) ? o0 : (wi == 1) ? o1 : o2;
    float4 v = *(const float4*)&s[i];
    bf16x4 o;
    o.x = (__bf16)v.x; o.y = (__bf16)v.y; o.z = (__bf16)v.z; o.w = (__bf16)v.w;
    *(bf16x4*)&d[i] = o;
}

// ---------------- fused QKV projection GEMM (m97 structure) ----------------
__global__ __launch_bounds__(256, 2) void qkv_gemm(const __bf16* __restrict__ A,
                                                   const __bf16* __restrict__ Wq,
                                                   const __bf16* __restrict__ Wk,
                                                   const __bf16* __restrict__ Wv,
                                                   const float* __restrict__ bq,
                                                   const float* __restrict__ bk,
                                                   const float* __restrict__ bv,
                                                   __bf16* __restrict__ Qo,
                                                   __bf16* __restrict__ Ko,
                                                   _Float16* __restrict__ Vt) {
    const int tng = blockIdx.x * 128, tm = blockIdx.y * 128;
    const int wsel = tng >> 10, tn = tng & 1023;
    const __bf16* W = (wsel == 0) ? Wq : (wsel == 1) ? Wk : Wv;
    const float* bias = (wsel == 0) ? bq : (wsel == 1) ? bk : bv;
    __shared__ __bf16 As[128 * 32];
    __shared__ __bf16 Bs[128 * 32];
    const int tid = threadIdx.x, wid = tid >> 6, lane = tid & 63;
    const int l15 = lane & 15, quad = lane >> 4;
    const int wm = (wid >> 1) * 64, wn = (wid & 1) * 64;
    floatx4 acc[4][4] = {};
    for (int k0 = 0; k0 < DIM; k0 += 32) {
        __syncthreads();
#pragma unroll
        for (int i = 0; i < 2; ++i) {
            int slot = i * 256 + tid;
            int r = slot >> 2, c8 = (slot & 3) * 8;
            g2l16(&A[(size_t)(tm + r) * DIM + k0 + c8], &As[slot * 8]);
            g2l16(&W[(size_t)(tn + r) * DIM + k0 + c8], &Bs[slot * 8]);
        }
        __syncthreads();
        bf16x8 af[4], bf[4];
#pragma unroll
        for (int t = 0; t < 4; ++t) {
            af[t] = *(const bf16x8*)&As[(wm + t * 16 + l15) * 32 + quad * 8];
            bf[t] = *(const bf16x8*)&Bs[(wn + t * 16 + l15) * 32 + quad * 8];
        }
#pragma unroll
        for (int im = 0; im < 4; ++im)
#pragma unroll
            for (int in = 0; in < 4; ++in)
                acc[im][in] = __builtin_amdgcn_mfma_f32_16x16x32_bf16(af[im], bf[in], acc[im][in], 0, 0, 0);
    }
    if (wsel < 2) {
        __bf16* O = wsel ? Ko : Qo;
#pragma unroll
        for (int im = 0; im < 4; ++im)
#pragma unroll
            for (int in = 0; in < 4; ++in)
#pragma unroll
                for (int r = 0; r < 4; ++r) {
                    int row = tm + wm + im * 16 + quad * 4 + r;
                    int col = tn + wn + in * 16 + l15;
                    O[(size_t)row * DIM + col] = (__bf16)(acc[im][in][r] + bias[col]);
                }
    } else {
#pragma unroll
        for (int im = 0; im < 4; ++im)
#pragma unroll
            for (int in = 0; in < 4; ++in) {
                int cv = tn + wn + in * 16 + l15;
                int row4 = tm + wm + im * 16 + quad * 4;
                float bv_ = bias[cv];
                f16x4 o;
#pragma unroll
                for (int r = 0; r < 4; ++r) o[r] = (_Float16)(acc[im][in][r] + bv_);
                *(f16x4*)&Vt[(size_t)cv * MTOT + row4] = o;
            }
    }
}

// ---------------- pass 1: rd = 1/sum_h exp(s/8)  (f16 out), 8-wave blocks ----------------
__global__ __launch_bounds__(512, 8) void den8(const __bf16* __restrict__ Q,
                                               const __bf16* __restrict__ Km,
                                               _Float16* __restrict__ rd) {
    const int kt = blockIdx.x * 64, qt = blockIdx.y * 128, b = blockIdx.z;
    __shared__ __bf16 Ks[2][2 * 2 * 64 * 32];  // 2 bufs x 16 KB
    const int tid = threadIdx.x, wid = tid >> 6, lane = tid & 63;
    const int l15 = lane & 15, quad = lane >> 4;
    const int kswz = ((lane >> 1) & 3) << 3;  // element offset XOR for reads
    const int wq = wid * 16;
    floatx4 dsum[4] = {};
    const size_t qrow = (size_t)(b * S_LEN + qt + wq + l15) * DIM;
    const size_t kbase = (size_t)(b * S_LEN + kt) * DIM;

#pragma unroll
    for (int i = 0; i < 2; ++i) {
        int slot = i * 512 + tid;
        int hs = slot >> 9, rem = slot & 511;
        int p = rem >> 8, rem2 = rem & 255;
        int r = rem2 >> 2;
        int c8 = (((rem2 & 3) ^ ((rem2 >> 3) & 3)) * 8);  // pre-swizzled global slot
        g2l16(&Km[kbase + (size_t)r * DIM + hs * HD + p * 32 + c8], &Ks[0][slot * 8]);
    }
    for (int hh = 0; hh < 8; ++hh) {
        const int cur = hh & 1, nxt = cur ^ 1;
        __syncthreads();
        bf16x8 af[2][2];
#pragma unroll
        for (int hs = 0; hs < 2; ++hs) {
            af[hs][0] = *(const bf16x8*)&Q[qrow + (hh * 2 + hs) * HD + quad * 8];
            af[hs][1] = *(const bf16x8*)&Q[qrow + (hh * 2 + hs) * HD + 32 + quad * 8];
        }
        if (hh + 1 < 8) {
#pragma unroll
            for (int i = 0; i < 2; ++i) {
                int slot = i * 512 + tid;
                int hs = slot >> 9, rem = slot & 511;
                int p = rem >> 8, rem2 = rem & 255;
                int r = rem2 >> 2;
                int c8 = (((rem2 & 3) ^ ((rem2 >> 3) & 3)) * 8);
                g2l16(&Km[kbase + (size_t)r * DIM + ((hh + 1) * 2 + hs) * HD + p * 32 + c8],
                      &Ks[nxt][slot * 8]);
            }
        }
#pragma unroll
        for (int hs = 0; hs < 2; ++hs) {
#pragma unroll
            for (int n = 0; n < 4; ++n) {
                bf16x8 b0 = *(const bf16x8*)&Ks[cur][hs * 4096 + (n * 16 + l15) * 32 + ((quad * 8) ^ kswz)];
                bf16x8 b1 = *(const bf16x8*)&Ks[cur][hs * 4096 + 2048 + (n * 16 + l15) * 32 + ((quad * 8) ^ kswz)];
                floatx4 acc = {};
                acc = __builtin_amdgcn_mfma_f32_16x16x32_bf16(af[hs][0], b0, acc, 0, 0, 0);
                acc = __builtin_amdgcn_mfma_f32_16x16x32_bf16(af[hs][1], b1, acc, 0, 0, 0);
                floatx4 sc = acc * C_EXP;
                floatx4 e;
#pragma unroll
                for (int r = 0; r < 4; ++r) e[r] = fast_exp2(sc[r]);
                dsum[n] += e;
            }
        }
    }
#pragma unroll
    for (int n = 0; n < 4; ++n)
#pragma unroll
        for (int r = 0; r < 4; ++r) {
            int q = qt + wq + quad * 4 + r;
            int k = kt + n * 16 + l15;
            rd[(size_t)(b * S_LEN + q) * S_LEN + k] = (_Float16)(1.0f / dsum[n][r]);
        }
}

// ---------------- pass 2a: 4-way K split, two heads, single-buffered V ----------------
__global__ __launch_bounds__(512, 4) void attn4h(const __bf16* __restrict__ Q,
                                                 const __bf16* __restrict__ Km,
                                                 const _Float16* __restrict__ Vt,
                                                 const _Float16* __restrict__ rd,
                                                 _Float16* __restrict__ AO1,
                                                 _Float16* __restrict__ AO2,
                                                 _Float16* __restrict__ AO3,
                                                 _Float16* __restrict__ AO4) {
    const int qt = (blockIdx.x >> 2) * 128, ks = blockIdx.x & 3;
    const int h0 = blockIdx.y * 2, b = blockIdx.z;  // heads h0, h0+1
    __shared__ __bf16 Ks[2][2 * 2 * 64 * 32];   // [buf][head][panel][tok][32], 16KB/buf (swizzled)
    __shared__ _Float16 Vts[2 * 64 * 72];       // SINGLE buf: [head][d][tok+pad], 18KB
    const int tid = threadIdx.x, wid = tid >> 6, lane = tid & 63;
    const int l15 = lane & 15, quad = lane >> 4;
    const int kswz = ((lane >> 1) & 3) << 3;
    const int wq = wid * 16;
    const size_t qrow = (size_t)(b * S_LEN + qt + wq + l15) * DIM + h0 * HD;
    bf16x8 qf[2][2];
    qf[0][0] = *(const bf16x8*)&Q[qrow + quad * 8];
    qf[0][1] = *(const bf16x8*)&Q[qrow + 32 + quad * 8];
    qf[1][0] = *(const bf16x8*)&Q[qrow + HD + quad * 8];
    qf[1][1] = *(const bf16x8*)&Q[qrow + HD + 32 + quad * 8];
    const _Float16* rdrow = &rd[(size_t)(b * S_LEN + qt + wq + l15) * S_LEN];
    floatx4 oacc[2][4] = {};
    const int kt0 = ks * (S_LEN / 4);
    const size_t kdim = (size_t)b * S_LEN * DIM;
    const int vr = tid >> 3, vc = (tid & 7) * 8;

#define STAGE_K4(BUF, KT_)                                                           \
    {                                                                                \
        _Pragma("unroll")                                                            \
        for (int i = 0; i < 2; ++i) {                                                \
            int slot = i * 512 + tid;                                                \
            int hh = slot >> 9, rem = slot & 511;                                    \
            int p = rem >> 8, rem2 = rem & 255;                                      \
            int r = rem2 >> 2;                                                       \
            int c8 = (((rem2 & 3) ^ ((rem2 >> 3) & 3)) * 8);                         \
            g2l16(&Km[kdim + (size_t)((KT_) + r) * DIM + (h0 + hh) * HD + p * 32 + c8], \
                  &Ks[BUF][slot * 8]);                                               \
        }                                                                            \
    }

    {
        f16x8 v0 = *(const f16x8*)&Vt[(size_t)(h0 * HD + vr) * MTOT + b * S_LEN + kt0 + vc];
        f16x8 v1 = *(const f16x8*)&Vt[(size_t)((h0 + 1) * HD + vr) * MTOT + b * S_LEN + kt0 + vc];
        STAGE_K4(0, kt0);
        *(f16x8*)&Vts[vr * 72 + vc] = v0;
        *(f16x8*)&Vts[4608 + vr * 72 + vc] = v1;
    }
    for (int it = 0; it < 8; ++it) {
        const int cur = it & 1, nxt = cur ^ 1;
        const int kt = kt0 + it * 64;
        __syncthreads();  // B1: K(it) staged, V(it) commits visible
        f16x4 rv[4];
#pragma unroll
        for (int mp = 0; mp < 4; ++mp)
            rv[mp] = *(const f16x4*)&rdrow[kt + mp * 16 + quad * 4];
        f16x8 vt0, vt1;
        const bool has_next = (it + 1 < 8);
        if (has_next) {
            const int ktn = kt + 64;
            vt0 = *(const f16x8*)&Vt[(size_t)(h0 * HD + vr) * MTOT + b * S_LEN + ktn + vc];
            vt1 = *(const f16x8*)&Vt[(size_t)((h0 + 1) * HD + vr) * MTOT + b * S_LEN + ktn + vc];
            STAGE_K4(nxt, ktn);
        }
        __builtin_amdgcn_s_setprio(1);
#pragma unroll
        for (int mp = 0; mp < 4; ++mp) {
            const int krow = (mp * 16 + l15) * 32 + ((quad * 8) ^ kswz);
            f16x4 pa[2];
#pragma unroll
            for (int hh = 0; hh < 2; ++hh) {
                bf16x8 kf0 = *(const bf16x8*)&Ks[cur][hh * 4096 + krow];
                bf16x8 kf1 = *(const bf16x8*)&Ks[cur][hh * 4096 + 2048 + krow];
                floatx4 s = {};
                s = __builtin_amdgcn_mfma_f32_16x16x32_bf16(kf0, qf[hh][0], s, 0, 0, 0);
                s = __builtin_amdgcn_mfma_f32_16x16x32_bf16(kf1, qf[hh][1], s, 0, 0, 0);
                floatx4 sc = s * C_EXP;
                f16x2 p01 = pk_cvt(fast_exp2(sc[0]), fast_exp2(sc[1]));
                f16x2 p23 = pk_cvt(fast_exp2(sc[2]), fast_exp2(sc[3]));
                f16x4 p = __builtin_shufflevector(p01, p23, 0, 1, 2, 3);
                pa[hh] = p * rv[mp];
            }
#pragma unroll
            for (int hh = 0; hh < 2; ++hh)
#pragma unroll
                for (int n = 0; n < 4; ++n) {
                    f16x4 vb = *(const f16x4*)&Vts[hh * 4608 + (n * 16 + l15) * 72 + mp * 16 + quad * 4];
                    oacc[hh][n] = __builtin_amdgcn_mfma_f32_16x16x16f16(pa[hh], vb, oacc[hh][n], 0, 0, 0);
                }
        }
        __builtin_amdgcn_s_setprio(0);
        if (has_next) {
            __syncthreads();  // B2: all waves done reading V(it)
            *(f16x8*)&Vts[vr * 72 + vc] = vt0;
            *(f16x8*)&Vts[4608 + vr * 72 + vc] = vt1;
        }
    }
#undef STAGE_K4
    _Float16* AO = (ks == 0) ? AO1 : (ks == 1) ? AO2 : (ks == 2) ? AO3 : AO4;
#pragma unroll
    for (int hh = 0; hh < 2; ++hh)
#pragma unroll
        for (int n = 0; n < 4; ++n)
#pragma unroll
            for (int r = 0; r < 4; ++r) {
                int row = qt + wq + quad * 4 + r;
                int col = (h0 + hh) * HD + n * 16 + l15;
                AO[(size_t)(b * S_LEN + row) * DIM + col] = (_Float16)oacc[hh][n][r];
            }
}

// ---------------- pass 2b: fallback, v11 exact (2-way split, double-buf V) ----------------
__global__ __launch_bounds__(512, 4) void attn2h(const __bf16* __restrict__ Q,
                                                 const __bf16* __restrict__ Km,
                                                 const _Float16* __restrict__ Vt,
                                                 const _Float16* __restrict__ rd,
                                                 _Float16* __restrict__ AO1,
                                                 _Float16* __restrict__ AO2) {
    const int qt = (blockIdx.x >> 1) * 128, ks = blockIdx.x & 1;
    const int h0 = blockIdx.y * 2, b = blockIdx.z;
    __shared__ __bf16 Ks[2][2 * 2 * 64 * 32];
    __shared__ _Float16 Vts[2][2 * 64 * 72];
    const int tid = threadIdx.x, wid = tid >> 6, lane = tid & 63;
    const int l15 = lane & 15, quad = lane >> 4;
    const int kswz = ((lane >> 1) & 3) << 3;
    const int wq = wid * 16;
    const size_t qrow = (size_t)(b * S_LEN + qt + wq + l15) * DIM + h0 * HD;
    bf16x8 qf[2][2];
    qf[0][0] = *(const bf16x8*)&Q[qrow + quad * 8];
    qf[0][1] = *(const bf16x8*)&Q[qrow + 32 + quad * 8];
    qf[1][0] = *(const bf16x8*)&Q[qrow + HD + quad * 8];
    qf[1][1] = *(const bf16x8*)&Q[qrow + HD + 32 + quad * 8];
    const _Float16* rdrow = &rd[(size_t)(b * S_LEN + qt + wq + l15) * S_LEN];
    floatx4 oacc[2][4] = {};
    const int kt0 = ks * (S_LEN / 2);
    const size_t kdim = (size_t)b * S_LEN * DIM;
    const int vr = tid >> 3, vc = (tid & 7) * 8;

#define STAGE_K2(BUF, KT_)                                                           \
    {                                                                                \
        _Pragma("unroll")                                                            \
        for (int i = 0; i < 2; ++i) {                                                \
            int slot = i * 512 + tid;                                                \
            int hh = slot >> 9, rem = slot & 511;                                    \
            int p = rem >> 8, rem2 = rem & 255;                                      \
            int r = rem2 >> 2;                                                       \
            int c8 = (((rem2 & 3) ^ ((rem2 >> 3) & 3)) * 8);                         \
            g2l16(&Km[kdim + (size_t)((KT_) + r) * DIM + (h0 + hh) * HD + p * 32 + c8], \
                  &Ks[BUF][slot * 8]);                                               \
        }                                                                            \
    }

    {
        f16x8 v0 = *(const f16x8*)&Vt[(size_t)(h0 * HD + vr) * MTOT + b * S_LEN + kt0 + vc];
        f16x8 v1 = *(const f16x8*)&Vt[(size_t)((h0 + 1) * HD + vr) * MTOT + b * S_LEN + kt0 + vc];
        STAGE_K2(0, kt0);
        *(f16x8*)&Vts[0][vr * 72 + vc] = v0;
        *(f16x8*)&Vts[0][4608 + vr * 72 + vc] = v1;
    }
    for (int it = 0; it < 16; ++it) {
        const int cur = it & 1, nxt = cur ^ 1;
        const int kt = kt0 + it * 64;
        __syncthreads();
        f16x4 rv[4];
#pragma unroll
        for (int mp = 0; mp < 4; ++mp)
            rv[mp] = *(const f16x4*)&rdrow[kt + mp * 16 + quad * 4];
        f16x8 vt0, vt1;
        const bool has_next = (it + 1 < 16);
        if (has_next) {
            const int ktn = kt + 64;
            vt0 = *(const f16x8*)&Vt[(size_t)(h0 * HD + vr) * MTOT + b * S_LEN + ktn + vc];
            vt1 = *(const f16x8*)&Vt[(size_t)((h0 + 1) * HD + vr) * MTOT + b * S_LEN + ktn + vc];
            STAGE_K2(nxt, ktn);
        }
#pragma unroll
        for (int mp = 0; mp < 4; ++mp) {
            const int krow = (mp * 16 + l15) * 32 + ((quad * 8) ^ kswz);
            f16x4 pa[2];
#pragma unroll
            for (int hh = 0; hh < 2; ++hh) {
                bf16x8 kf0 = *(const bf16x8*)&Ks[cur][hh * 4096 + krow];
                bf16x8 kf1 = *(const bf16x8*)&Ks[cur][hh * 4096 + 2048 + krow];
                floatx4 s = {};
                s = __builtin_amdgcn_mfma_f32_16x16x32_bf16(kf0, qf[hh][0], s, 0, 0, 0);
                s = __builtin_amdgcn_mfma_f32_16x16x32_bf16(kf1, qf[hh][1], s, 0, 0, 0);
                floatx4 sc = s * C_EXP;
                f16x2 p01 = pk_cvt(fast_exp2(sc[0]), fast_exp2(sc[1]));
                f16x2 p23 = pk_cvt(fast_exp2(sc[2]), fast_exp2(sc[3]));
                f16x4 p = __builtin_shufflevector(p01, p23, 0, 1, 2, 3);
                pa[hh] = p * rv[mp];
            }
#pragma unroll
            for (int hh = 0; hh < 2; ++hh)
#pragma unroll
                for (int n = 0; n < 4; ++n) {
                    f16x4 vb = *(const f16x4*)&Vts[cur][hh * 4608 + (n * 16 + l15) * 72 + mp * 16 + quad * 4];
                    oacc[hh][n] = __builtin_amdgcn_mfma_f32_16x16x16f16(pa[hh], vb, oacc[hh][n], 0, 0, 0);
                }
        }
        if (has_next) {
            *(f16x8*)&Vts[nxt][vr * 72 + vc] = vt0;
            *(f16x8*)&Vts[nxt][4608 + vr * 72 + vc] = vt1;
        }
    }
#undef STAGE_K2
    _Float16* AO = ks ? AO2 : AO1;
#pragma unroll
    for (int hh = 0; hh < 2; ++hh)
#pragma unroll
        for (int n = 0; n < 4; ++n)
#pragma unroll
            for (int r = 0; r < 4; ++r) {
                int row = qt + wq + quad * 4 + r;
                int col = (h0 + hh) * HD + n * 16 + l15;
                AO[(size_t)(b * S_LEN + row) * DIM + col] = (_Float16)oacc[hh][n][r];
            }
}

// ---------------- output projection, 4 partials ----------------
__global__ __launch_bounds__(256, 2) void gout4(const _Float16* __restrict__ A1,
                                                const _Float16* __restrict__ A2,
                                                const _Float16* __restrict__ A3,
                                                const _Float16* __restrict__ A4,
                                                const _Float16* __restrict__ Bw,
                                                const float* __restrict__ bias,
                                                float* __restrict__ C) {
    const int tm = blockIdx.y * 128, tn = blockIdx.x * 64;
    __shared__ _Float16 As1[2 * 128 * 32];
    __shared__ _Float16 As2[2 * 128 * 32];
    __shared__ _Float16 As3[2 * 128 * 32];
    __shared__ _Float16 As4[2 * 128 * 32];
    __shared__ _Float16 Bs[2 * 64 * 32];
    const int tid = threadIdx.x, wid = tid >> 6, lane = tid & 63;
    const int l15 = lane & 15, quad = lane >> 4;
    const int wm = (wid >> 1) * 64, wn = (wid & 1) * 32;
    floatx4 acc[4][2] = {};
    for (int k0 = 0; k0 < DIM; k0 += 64) {
        __syncthreads();
#pragma unroll
        for (int i = 0; i < 4; ++i) {
            int slot = i * 256 + tid;
            int p = slot >> 9, rem = slot & 511;
            int r = rem >> 2, c8 = (rem & 3) * 8;
            size_t ga = (size_t)(tm + r) * DIM + k0 + p * 32 + c8;
            g2l16(&A1[ga], &As1[slot * 8]);
            g2l16(&A2[ga], &As2[slot * 8]);
            g2l16(&A3[ga], &As3[slot * 8]);
            g2l16(&A4[ga], &As4[slot * 8]);
        }
#pragma unroll
        for (int i = 0; i < 2; ++i) {
            int slot = i * 256 + tid;
            int p = slot >> 8, rem = slot & 255;
            int r = rem >> 2, c8 = (rem & 3) * 8;
            g2l16(&Bw[(size_t)(tn + r) * DIM + k0 + p * 32 + c8], &Bs[slot * 8]);
        }
        __syncthreads();
#pragma unroll
        for (int kc = 0; kc < 2; ++kc) {
            f16x8 af[4], bf[2];
#pragma unroll
            for (int t = 0; t < 4; ++t) {
                int off = kc * 4096 + (wm + t * 16 + l15) * 32 + quad * 8;
                f16x8 a1 = *(const f16x8*)&As1[off];
                f16x8 a2 = *(const f16x8*)&As2[off];
                f16x8 a3 = *(const f16x8*)&As3[off];
                f16x8 a4 = *(const f16x8*)&As4[off];
                af[t] = (a1 + a2) + (a3 + a4);
            }
#pragma unroll
            for (int t = 0; t < 2; ++t)
                bf[t] = *(const f16x8*)&Bs[kc * 2048 + (wn + t * 16 + l15) * 32 + quad * 8];
#pragma unroll
            for (int im = 0; im < 4; ++im)
#pragma unroll
                for (int in = 0; in < 2; ++in)
                    acc[im][in] = __builtin_amdgcn_mfma_f32_16x16x32_f16(af[im], bf[in], acc[im][in], 0, 0, 0);
        }
    }
#pragma unroll
    for (int im = 0; im < 4; ++im)
#pragma unroll
        for (int in = 0; in < 2; ++in)
#pragma unroll
            for (int r = 0; r < 4; ++r) {
                int row = tm + wm + im * 16 + quad * 4 + r;
                int col = tn + wn + in * 16 + l15;
                C[(size_t)row * DIM + col] = acc[im][in][r] + bias[col];
            }
}

// ---------------- output projection, 2 partials (v11 exact) ----------------
__global__ __launch_bounds__(256, 2) void gout2(const _Float16* __restrict__ A1,
                                                const _Float16* __restrict__ A2,
                                                const _Float16* __restrict__ Bw,
                                                const float* __restrict__ bias,
                                                float* __restrict__ C) {
    const int tm = blockIdx.y * 128, tn = blockIdx.x * 64;
    __shared__ _Float16 As1[2 * 128 * 32];
    __shared__ _Float16 As2[2 * 128 * 32];
    __shared__ _Float16 Bs[2 * 64 * 32];
    const int tid = threadIdx.x, wid = tid >> 6, lane = tid & 63;
    const int l15 = lane & 15, quad = lane >> 4;
    const int wm = (wid >> 1) * 64, wn = (wid & 1) * 32;
    floatx4 acc[4][2] = {};
    for (int k0 = 0; k0 < DIM; k0 += 64) {
        __syncthreads();
#pragma unroll
        for (int i = 0; i < 4; ++i) {
            int slot = i * 256 + tid;
            int p = slot >> 9, rem = slot & 511;
            int r = rem >> 2, c8 = (rem & 3) * 8;
            size_t ga = (size_t)(tm + r) * DIM + k0 + p * 32 + c8;
            g2l16(&A1[ga], &As1[slot * 8]);
            g2l16(&A2[ga], &As2[slot * 8]);
        }
#pragma unroll
        for (int i = 0; i < 2; ++i) {
            int slot = i * 256 + tid;
            int p = slot >> 8, rem = slot & 255;
            int r = rem >> 2, c8 = (rem & 3) * 8;
            g2l16(&Bw[(size_t)(tn + r) * DIM + k0 + p * 32 + c8], &Bs[slot * 8]);
        }
        __syncthreads();
#pragma unroll
        for (int kc = 0; kc < 2; ++kc) {
            f16x8 af[4], bf[2];
#pragma unroll
            for (int t = 0; t < 4; ++t) {
                int off = kc * 4096 + (wm + t * 16 + l15) * 32 + quad * 8;
                f16x8 a1 = *(const f16x8*)&As1[off];
                f16x8 a2 = *(const f16x8*)&As2[off];
                af[t] = a1 + a2;
            }
#pragma unroll
            for (int t = 0; t < 2; ++t)
                bf[t] = *(const f16x8*)&Bs[kc * 2048 + (wn + t * 16 + l15) * 32 + quad * 8];
#pragma unroll
            for (int im = 0; im < 4; ++im)
#pragma unroll
                for (int in = 0; in < 2; ++in)
                    acc[im][in] = __builtin_amdgcn_mfma_f32_16x16x32_f16(af[im], bf[in], acc[im][in], 0, 0, 0);
        }
    }
#pragma unroll
    for (int im = 0; im < 4; ++im)
#pragma unroll
        for (int in = 0; in < 2; ++in)
#pragma unroll
            for (int r = 0; r < 4; ++r) {
                int row = tm + wm + im * 16 + quad * 4 + r;
                int col = tn + wn + in * 16 + l15;
                C[(size_t)row * DIM + col] = acc[im][in][r] + bias[col];
            }
}

extern "C" void kernel_launch(void* const* d_in, const int* in_sizes, int n_in,
                              void* d_out, int out_size, void* d_ws, size_t ws_size,
                              hipStream_t stream) {
    const float* x  = (const float*)d_in[0];
    const float* Wq = (const float*)d_in[1];
    const float* bq = (const float*)d_in[2];
    const float* Wk = (const float*)d_in[3];
    const float* bk = (const float*)d_in[4];
    const float* Wv = (const float*)d_in[5];
    const float* bv = (const float*)d_in[6];
    const float* Wo = (const float*)d_in[7];
    const float* bo = (const float*)d_in[8];
    float* out = (float*)d_out;

    char* ws = (char*)d_ws;
    const size_t MB = 1u << 20;
    __bf16*    xb  = (__bf16*)(ws);              // 8 MB (dead after qkv_gemm)
    __bf16*    Wqb = (__bf16*)(ws + 8 * MB);
    __bf16*    Wkb = (__bf16*)(ws + 10 * MB);
    __bf16*    Wvb = (__bf16*)(ws + 12 * MB);
    _Float16*  Wof = (_Float16*)(ws + 14 * MB);
    __bf16*    Qb  = (__bf16*)(ws + 16 * MB);    // 8 MB
    __bf16*    Kb  = (__bf16*)(ws + 24 * MB);    // 8 MB
    _Float16*  VtH = (_Float16*)(ws + 32 * MB);  // 8 MB
    _Float16*  rd  = (_Float16*)(ws + 40 * MB);  // 16 MB (f16, B*S*S) -- spans 40..56!
    _Float16*  AO1 = (_Float16*)(ws + 56 * MB);  // 8 MB
    _Float16*  AO2 = (_Float16*)(ws + 64 * MB);  // 8 MB
    _Float16*  AO3 = (_Float16*)(ws);            // 8 MB, reuses dead xb region
    _Float16*  AO4 = (_Float16*)(ws + 72 * MB);  // 8 MB, needs ws_size >= 80 MB

    const bool four = ws_size >= (size_t)80 * MB;

    cast_all<<<8192, 256, 0, stream>>>(x, Wq, Wk, Wv, Wo, xb, Wqb, Wkb, Wvb, Wof);

    qkv_gemm<<<dim3(24, 32), 256, 0, stream>>>(xb, Wqb, Wkb, Wvb, bq, bk, bv, Qb, Kb, VtH);

    den8<<<dim3(S_LEN / 64, S_LEN / 128, 2), 512, 0, stream>>>(Qb, Kb, rd);

    if (four) {
        attn4h<<<dim3((S_LEN / 128) * 4, NH / 2, 2), 512, 0, stream>>>(Qb, Kb, VtH, rd,
                                                                       AO1, AO2, AO3, AO4);
        gout4<<<dim3(DIM / 64, MTOT / 128), 256, 0, stream>>>(AO1, AO2, AO3, AO4, Wof, bo, out);
    } else {
        attn2h<<<dim3((S_LEN / 128) * 2, NH / 2, 2), 512, 0, stream>>>(Qb, Kb, VtH, rd, AO1, AO2);
        gout2<<<dim3(DIM / 64, MTOT / 128), 256, 0, stream>>>(AO1, AO2, Wof, bo, out);
    }
}

// Round 8
// 266.208 us; speedup vs baseline: 1.1878x; 1.0535x over previous
//
#include <hip/hip_runtime.h>
#include <hip/hip_bf16.h>
#include <cstdint>
#include <cstddef>

// B=2, S=2048, D=1024, H=16, HD=64.  softmax over HEAD axis.
// v15: revert to v11 structure (best: 256.2us; v14's 4-way split regressed --
//   occupancy is register-file-capped at ~2 blocks/CU, LDS savings moot).
//   Changes vs v11, all VALU-diet / scheduler:
//   (1) C_EXP (log2e/8) folded into Q at qkv_gemm epilogue -> den8/attn8
//       drop the floatx4 scale before every exp2 (32 VALU/tile/wave).
//       Softmax exact w.r.t. the scaled scores (num+den share s').
//   (2) s_setprio(1) around attn8 compute cluster (T5, m191 +4-7%;
//       v11 never tested it unconfounded).
//   K slot-swizzle retained. den8/cast/gout2 otherwise v11-exact.

typedef __bf16 bf16x8 __attribute__((ext_vector_type(8)));
typedef __bf16 bf16x4 __attribute__((ext_vector_type(4)));
typedef _Float16 f16x2 __attribute__((ext_vector_type(2)));
typedef _Float16 f16x4 __attribute__((ext_vector_type(4)));
typedef _Float16 f16x8 __attribute__((ext_vector_type(8)));
typedef float floatx4 __attribute__((ext_vector_type(4)));

#define S_LEN 2048
#define DIM 1024
#define NH 16
#define HD 64
#define MTOT 4096  // B * S
#define C_EXP 0.1803368801111244f  // log2(e)/8

__device__ __forceinline__ float fast_exp2(float x) { return __builtin_amdgcn_exp2f(x); }

__device__ __forceinline__ f16x2 pk_cvt(float a, float b) {
    return __builtin_bit_cast(f16x2, __builtin_amdgcn_cvt_pkrtz(a, b));
}

__device__ __forceinline__ void g2l16(const void* g, void* l) {
    __builtin_amdgcn_global_load_lds(
        (const __attribute__((address_space(1))) void*)g,
        (__attribute__((address_space(3))) void*)l, 16, 0, 0);
}

// ---------------- fused cast: x -> bf16, Wq/Wk/Wv -> bf16, Wo -> f16 ----------------
__global__ void cast_all(const float* __restrict__ x,
                         const float* __restrict__ w0, const float* __restrict__ w1,
                         const float* __restrict__ w2, const float* __restrict__ w3,
                         __bf16* __restrict__ xb,
                         __bf16* __restrict__ o0, __bf16* __restrict__ o1,
                         __bf16* __restrict__ o2, _Float16* __restrict__ o3) {
    int bid = blockIdx.x;
    if (bid < 4096) {
        int i = (bid * 256 + threadIdx.x) * 4;
        float4 v = *(const float4*)&x[i];
        bf16x4 o;
        o.x = (__bf16)v.x; o.y = (__bf16)v.y; o.z = (__bf16)v.z; o.w = (__bf16)v.w;
        *(bf16x4*)&xb[i] = o;
        return;
    }
    bid -= 4096;
    int wi = bid >> 10;
    int i = ((bid & 1023) * 256 + threadIdx.x) * 4;
    if (wi == 3) {
        float4 v = *(const float4*)&w3[i];
        f16x4 o;
        o[0] = (_Float16)v.x; o[1] = (_Float16)v.y; o[2] = (_Float16)v.z; o[3] = (_Float16)v.w;
        *(f16x4*)&o3[i] = o;
        return;
    }
    const float* s = (wi == 0) ? w0 : (wi == 1) ? w1 : w2;
    __bf16* d = (wi == 0) ? o0 : (wi == 1) ? o1 : o2;
    float4 v = *(const float4*)&s[i];
    bf16x4 o;
    o.x = (__bf16)v.x; o.y = (__bf16)v.y; o.z = (__bf16)v.z; o.w = (__bf16)v.w;
    *(bf16x4*)&d[i] = o;
}

// ---------------- fused QKV projection GEMM (m97 structure) ----------------
// Qo epilogue is pre-scaled by C_EXP so den8/attn8 can exp2 the MFMA output directly.
__global__ __launch_bounds__(256, 2) void qkv_gemm(const __bf16* __restrict__ A,
                                                   const __bf16* __restrict__ Wq,
                                                   const __bf16* __restrict__ Wk,
                                                   const __bf16* __restrict__ Wv,
                                                   const float* __restrict__ bq,
                                                   const float* __restrict__ bk,
                                                   const float* __restrict__ bv,
                                                   __bf16* __restrict__ Qo,
                                                   __bf16* __restrict__ Ko,
                                                   _Float16* __restrict__ Vt) {
    const int tng = blockIdx.x * 128, tm = blockIdx.y * 128;
    const int wsel = tng >> 10, tn = tng & 1023;
    const __bf16* W = (wsel == 0) ? Wq : (wsel == 1) ? Wk : Wv;
    const float* bias = (wsel == 0) ? bq : (wsel == 1) ? bk : bv;
    __shared__ __bf16 As[128 * 32];
    __shared__ __bf16 Bs[128 * 32];
    const int tid = threadIdx.x, wid = tid >> 6, lane = tid & 63;
    const int l15 = lane & 15, quad = lane >> 4;
    const int wm = (wid >> 1) * 64, wn = (wid & 1) * 64;
    floatx4 acc[4][4] = {};
    for (int k0 = 0; k0 < DIM; k0 += 32) {
        __syncthreads();
#pragma unroll
        for (int i = 0; i < 2; ++i) {
            int slot = i * 256 + tid;
            int r = slot >> 2, c8 = (slot & 3) * 8;
            g2l16(&A[(size_t)(tm + r) * DIM + k0 + c8], &As[slot * 8]);
            g2l16(&W[(size_t)(tn + r) * DIM + k0 + c8], &Bs[slot * 8]);
        }
        __syncthreads();
        bf16x8 af[4], bf[4];
#pragma unroll
        for (int t = 0; t < 4; ++t) {
            af[t] = *(const bf16x8*)&As[(wm + t * 16 + l15) * 32 + quad * 8];
            bf[t] = *(const bf16x8*)&Bs[(wn + t * 16 + l15) * 32 + quad * 8];
        }
#pragma unroll
        for (int im = 0; im < 4; ++im)
#pragma unroll
            for (int in = 0; in < 4; ++in)
                acc[im][in] = __builtin_amdgcn_mfma_f32_16x16x32_bf16(af[im], bf[in], acc[im][in], 0, 0, 0);
    }
    if (wsel < 2) {
        __bf16* O = wsel ? Ko : Qo;
        const float qs = (wsel == 0) ? C_EXP : 1.0f;  // fold log2(e)/8 into Q
#pragma unroll
        for (int im = 0; im < 4; ++im)
#pragma unroll
            for (int in = 0; in < 4; ++in)
#pragma unroll
                for (int r = 0; r < 4; ++r) {
                    int row = tm + wm + im * 16 + quad * 4 + r;
                    int col = tn + wn + in * 16 + l15;
                    O[(size_t)row * DIM + col] = (__bf16)((acc[im][in][r] + bias[col]) * qs);
                }
    } else {
#pragma unroll
        for (int im = 0; im < 4; ++im)
#pragma unroll
            for (int in = 0; in < 4; ++in) {
                int cv = tn + wn + in * 16 + l15;
                int row4 = tm + wm + im * 16 + quad * 4;
                float bv_ = bias[cv];
                f16x4 o;
#pragma unroll
                for (int r = 0; r < 4; ++r) o[r] = (_Float16)(acc[im][in][r] + bv_);
                *(f16x4*)&Vt[(size_t)cv * MTOT + row4] = o;
            }
    }
}

// ---------------- pass 1: rd = 1/sum_h exp2(s')  (f16 out), 8-wave blocks ----------------
// Q is pre-scaled by C_EXP, so exp2 applies directly to the MFMA output.
__global__ __launch_bounds__(512, 8) void den8(const __bf16* __restrict__ Q,
                                               const __bf16* __restrict__ Km,
                                               _Float16* __restrict__ rd) {
    const int kt = blockIdx.x * 64, qt = blockIdx.y * 128, b = blockIdx.z;
    __shared__ __bf16 Ks[2][2 * 2 * 64 * 32];  // 2 bufs x 16 KB
    const int tid = threadIdx.x, wid = tid >> 6, lane = tid & 63;
    const int l15 = lane & 15, quad = lane >> 4;
    const int kswz = ((lane >> 1) & 3) << 3;  // element offset XOR for reads
    const int wq = wid * 16;
    floatx4 dsum[4] = {};
    const size_t qrow = (size_t)(b * S_LEN + qt + wq + l15) * DIM;
    const size_t kbase = (size_t)(b * S_LEN + kt) * DIM;

#pragma unroll
    for (int i = 0; i < 2; ++i) {
        int slot = i * 512 + tid;
        int hs = slot >> 9, rem = slot & 511;
        int p = rem >> 8, rem2 = rem & 255;
        int r = rem2 >> 2;
        int c8 = (((rem2 & 3) ^ ((rem2 >> 3) & 3)) * 8);  // pre-swizzled global slot
        g2l16(&Km[kbase + (size_t)r * DIM + hs * HD + p * 32 + c8], &Ks[0][slot * 8]);
    }
    for (int hh = 0; hh < 8; ++hh) {
        const int cur = hh & 1, nxt = cur ^ 1;
        __syncthreads();
        bf16x8 af[2][2];
#pragma unroll
        for (int hs = 0; hs < 2; ++hs) {
            af[hs][0] = *(const bf16x8*)&Q[qrow + (hh * 2 + hs) * HD + quad * 8];
            af[hs][1] = *(const bf16x8*)&Q[qrow + (hh * 2 + hs) * HD + 32 + quad * 8];
        }
        if (hh + 1 < 8) {
#pragma unroll
            for (int i = 0; i < 2; ++i) {
                int slot = i * 512 + tid;
                int hs = slot >> 9, rem = slot & 511;
                int p = rem >> 8, rem2 = rem & 255;
                int r = rem2 >> 2;
                int c8 = (((rem2 & 3) ^ ((rem2 >> 3) & 3)) * 8);
                g2l16(&Km[kbase + (size_t)r * DIM + ((hh + 1) * 2 + hs) * HD + p * 32 + c8],
                      &Ks[nxt][slot * 8]);
            }
        }
#pragma unroll
        for (int hs = 0; hs < 2; ++hs) {
#pragma unroll
            for (int n = 0; n < 4; ++n) {
                bf16x8 b0 = *(const bf16x8*)&Ks[cur][hs * 4096 + (n * 16 + l15) * 32 + ((quad * 8) ^ kswz)];
                bf16x8 b1 = *(const bf16x8*)&Ks[cur][hs * 4096 + 2048 + (n * 16 + l15) * 32 + ((quad * 8) ^ kswz)];
                floatx4 acc = {};
                acc = __builtin_amdgcn_mfma_f32_16x16x32_bf16(af[hs][0], b0, acc, 0, 0, 0);
                acc = __builtin_amdgcn_mfma_f32_16x16x32_bf16(af[hs][1], b1, acc, 0, 0, 0);
                floatx4 e;
#pragma unroll
                for (int r = 0; r < 4; ++r) e[r] = fast_exp2(acc[r]);
                dsum[n] += e;
            }
        }
    }
#pragma unroll
    for (int n = 0; n < 4; ++n)
#pragma unroll
        for (int r = 0; r < 4; ++r) {
            int q = qt + wq + quad * 4 + r;
            int k = kt + n * 16 + l15;
            rd[(size_t)(b * S_LEN + q) * S_LEN + k] = (_Float16)(1.0f / dsum[n][r]);
        }
}

// ---------------- pass 2: partial AO, TWO heads per block (v11 form) ----------------
__global__ __launch_bounds__(512, 4) void attn8(const __bf16* __restrict__ Q,
                                                const __bf16* __restrict__ Km,
                                                const _Float16* __restrict__ Vt,
                                                const _Float16* __restrict__ rd,
                                                _Float16* __restrict__ AO1,
                                                _Float16* __restrict__ AO2) {
    const int qt = (blockIdx.x >> 1) * 128, ks = blockIdx.x & 1;
    const int h0 = blockIdx.y * 2, b = blockIdx.z;  // heads h0, h0+1
    __shared__ __bf16 Ks[2][2 * 2 * 64 * 32];   // [buf][head][panel][tok][32], 16KB/buf (swizzled)
    __shared__ _Float16 Vts[2][2 * 64 * 72];    // [buf][head][d][tok+pad], 18KB/buf
    const int tid = threadIdx.x, wid = tid >> 6, lane = tid & 63;
    const int l15 = lane & 15, quad = lane >> 4;
    const int kswz = ((lane >> 1) & 3) << 3;  // element offset XOR for reads
    const int wq = wid * 16;
    const size_t qrow = (size_t)(b * S_LEN + qt + wq + l15) * DIM + h0 * HD;
    bf16x8 qf[2][2];
    qf[0][0] = *(const bf16x8*)&Q[qrow + quad * 8];
    qf[0][1] = *(const bf16x8*)&Q[qrow + 32 + quad * 8];
    qf[1][0] = *(const bf16x8*)&Q[qrow + HD + quad * 8];
    qf[1][1] = *(const bf16x8*)&Q[qrow + HD + 32 + quad * 8];
    const _Float16* rdrow = &rd[(size_t)(b * S_LEN + qt + wq + l15) * S_LEN];
    floatx4 oacc[2][4] = {};
    const int kt0 = ks * (S_LEN / 2);
    const size_t kdim = (size_t)b * S_LEN * DIM;
    const int vr = tid >> 3, vc = (tid & 7) * 8;

#define STAGE_K(BUF, KT_)                                                            \
    {                                                                                \
        _Pragma("unroll")                                                            \
        for (int i = 0; i < 2; ++i) {                                                \
            int slot = i * 512 + tid;                                                \
            int hh = slot >> 9, rem = slot & 511;                                    \
            int p = rem >> 8, rem2 = rem & 255;                                      \
            int r = rem2 >> 2;                                                       \
            int c8 = (((rem2 & 3) ^ ((rem2 >> 3) & 3)) * 8);                         \
            g2l16(&Km[kdim + (size_t)((KT_) + r) * DIM + (h0 + hh) * HD + p * 32 + c8], \
                  &Ks[BUF][slot * 8]);                                               \
        }                                                                            \
    }

    // prologue: stage kt0 into buf 0
    {
        f16x8 v0 = *(const f16x8*)&Vt[(size_t)(h0 * HD + vr) * MTOT + b * S_LEN + kt0 + vc];
        f16x8 v1 = *(const f16x8*)&Vt[(size_t)((h0 + 1) * HD + vr) * MTOT + b * S_LEN + kt0 + vc];
        STAGE_K(0, kt0);
        *(f16x8*)&Vts[0][vr * 72 + vc] = v0;
        *(f16x8*)&Vts[0][4608 + vr * 72 + vc] = v1;
    }
    for (int it = 0; it < 16; ++it) {
        const int cur = it & 1, nxt = cur ^ 1;
        const int kt = kt0 + it * 64;
        __syncthreads();
        // rv for this iter -- SHARED by both heads (denominator is per (q,k))
        f16x4 rv[4];
#pragma unroll
        for (int mp = 0; mp < 4; ++mp)
            rv[mp] = *(const f16x4*)&rdrow[kt + mp * 16 + quad * 4];
        // issue next tile's loads (V kept in regs; committed to LDS after compute)
        f16x8 vt0, vt1;
        const bool has_next = (it + 1 < 16);
        if (has_next) {
            const int ktn = kt + 64;
            vt0 = *(const f16x8*)&Vt[(size_t)(h0 * HD + vr) * MTOT + b * S_LEN + ktn + vc];
            vt1 = *(const f16x8*)&Vt[(size_t)((h0 + 1) * HD + vr) * MTOT + b * S_LEN + ktn + vc];
            STAGE_K(nxt, ktn);
        }
        // compute current tile, both heads (Q pre-scaled: exp2 directly on s)
        __builtin_amdgcn_s_setprio(1);
#pragma unroll
        for (int mp = 0; mp < 4; ++mp) {
            const int krow = (mp * 16 + l15) * 32 + ((quad * 8) ^ kswz);
            f16x4 pa[2];
#pragma unroll
            for (int hh = 0; hh < 2; ++hh) {
                bf16x8 kf0 = *(const bf16x8*)&Ks[cur][hh * 4096 + krow];
                bf16x8 kf1 = *(const bf16x8*)&Ks[cur][hh * 4096 + 2048 + krow];
                floatx4 s = {};
                s = __builtin_amdgcn_mfma_f32_16x16x32_bf16(kf0, qf[hh][0], s, 0, 0, 0);
                s = __builtin_amdgcn_mfma_f32_16x16x32_bf16(kf1, qf[hh][1], s, 0, 0, 0);
                f16x2 p01 = pk_cvt(fast_exp2(s[0]), fast_exp2(s[1]));
                f16x2 p23 = pk_cvt(fast_exp2(s[2]), fast_exp2(s[3]));
                f16x4 p = __builtin_shufflevector(p01, p23, 0, 1, 2, 3);
                pa[hh] = p * rv[mp];  // v_pk_mul_f16 x2
            }
#pragma unroll
            for (int hh = 0; hh < 2; ++hh)
#pragma unroll
                for (int n = 0; n < 4; ++n) {
                    f16x4 vb = *(const f16x4*)&Vts[cur][hh * 4608 + (n * 16 + l15) * 72 + mp * 16 + quad * 4];
                    oacc[hh][n] = __builtin_amdgcn_mfma_f32_16x16x16f16(pa[hh], vb, oacc[hh][n], 0, 0, 0);
                }
        }
        __builtin_amdgcn_s_setprio(0);
        // commit next V tile to LDS (vmcnt wait lands here, after compute)
        if (has_next) {
            *(f16x8*)&Vts[nxt][vr * 72 + vc] = vt0;
            *(f16x8*)&Vts[nxt][4608 + vr * 72 + vc] = vt1;
        }
    }
#undef STAGE_K
    _Float16* AO = ks ? AO2 : AO1;
#pragma unroll
    for (int hh = 0; hh < 2; ++hh)
#pragma unroll
        for (int n = 0; n < 4; ++n)
#pragma unroll
            for (int r = 0; r < 4; ++r) {
                int row = qt + wq + quad * 4 + r;
                int col = (h0 + hh) * HD + n * 16 + l15;
                AO[(size_t)(b * S_LEN + row) * DIM + col] = (_Float16)oacc[hh][n][r];
            }
}

// ---------------- output projection: C = (AO1+AO2) @ Wo^T + bo ----------------
__global__ __launch_bounds__(256, 2) void gemm_out2(const _Float16* __restrict__ A1,
                                                    const _Float16* __restrict__ A2,
                                                    const _Float16* __restrict__ Bw,
                                                    const float* __restrict__ bias,
                                                    float* __restrict__ C) {
    const int tm = blockIdx.y * 128, tn = blockIdx.x * 64;
    __shared__ _Float16 As1[2 * 128 * 32];
    __shared__ _Float16 As2[2 * 128 * 32];
    __shared__ _Float16 Bs[2 * 64 * 32];
    const int tid = threadIdx.x, wid = tid >> 6, lane = tid & 63;
    const int l15 = lane & 15, quad = lane >> 4;
    const int wm = (wid >> 1) * 64, wn = (wid & 1) * 32;
    floatx4 acc[4][2] = {};
    for (int k0 = 0; k0 < DIM; k0 += 64) {
        __syncthreads();
#pragma unroll
        for (int i = 0; i < 4; ++i) {
            int slot = i * 256 + tid;
            int p = slot >> 9, rem = slot & 511;
            int r = rem >> 2, c8 = (rem & 3) * 8;
            size_t ga = (size_t)(tm + r) * DIM + k0 + p * 32 + c8;
            g2l16(&A1[ga], &As1[slot * 8]);
            g2l16(&A2[ga], &As2[slot * 8]);
        }
#pragma unroll
        for (int i = 0; i < 2; ++i) {
            int slot = i * 256 + tid;
            int p = slot >> 8, rem = slot & 255;
            int r = rem >> 2, c8 = (rem & 3) * 8;
            g2l16(&Bw[(size_t)(tn + r) * DIM + k0 + p * 32 + c8], &Bs[slot * 8]);
        }
        __syncthreads();
#pragma unroll
        for (int kc = 0; kc < 2; ++kc) {
            f16x8 af[4], bf[2];
#pragma unroll
            for (int t = 0; t < 4; ++t) {
                int off = kc * 4096 + (wm + t * 16 + l15) * 32 + quad * 8;
                f16x8 a1 = *(const f16x8*)&As1[off];
                f16x8 a2 = *(const f16x8*)&As2[off];
                af[t] = a1 + a2;
            }
#pragma unroll
            for (int t = 0; t < 2; ++t)
                bf[t] = *(const f16x8*)&Bs[kc * 2048 + (wn + t * 16 + l15) * 32 + quad * 8];
#pragma unroll
            for (int im = 0; im < 4; ++im)
#pragma unroll
                for (int in = 0; in < 2; ++in)
                    acc[im][in] = __builtin_amdgcn_mfma_f32_16x16x32_f16(af[im], bf[in], acc[im][in], 0, 0, 0);
        }
    }
#pragma unroll
    for (int im = 0; im < 4; ++im)
#pragma unroll
        for (int in = 0; in < 2; ++in)
#pragma unroll
            for (int r = 0; r < 4; ++r) {
                int row = tm + wm + im * 16 + quad * 4 + r;
                int col = tn + wn + in * 16 + l15;
                C[(size_t)row * DIM + col] = acc[im][in][r] + bias[col];
            }
}

extern "C" void kernel_launch(void* const* d_in, const int* in_sizes, int n_in,
                              void* d_out, int out_size, void* d_ws, size_t ws_size,
                              hipStream_t stream) {
    const float* x  = (const float*)d_in[0];
    const float* Wq = (const float*)d_in[1];
    const float* bq = (const float*)d_in[2];
    const float* Wk = (const float*)d_in[3];
    const float* bk = (const float*)d_in[4];
    const float* Wv = (const float*)d_in[5];
    const float* bv = (const float*)d_in[6];
    const float* Wo = (const float*)d_in[7];
    const float* bo = (const float*)d_in[8];
    float* out = (float*)d_out;

    char* ws = (char*)d_ws;
    const size_t MB = 1u << 20;
    __bf16*    xb  = (__bf16*)(ws);              // 8 MB
    __bf16*    Wqb = (__bf16*)(ws + 8 * MB);
    __bf16*    Wkb = (__bf16*)(ws + 10 * MB);
    __bf16*    Wvb = (__bf16*)(ws + 12 * MB);
    _Float16*  Wof = (_Float16*)(ws + 14 * MB);
    __bf16*    Qb  = (__bf16*)(ws + 16 * MB);    // 8 MB
    __bf16*    Kb  = (__bf16*)(ws + 24 * MB);    // 8 MB
    _Float16*  VtH = (_Float16*)(ws + 32 * MB);  // 8 MB
    _Float16*  rd  = (_Float16*)(ws + 40 * MB);  // 16 MB (f16, B*S*S) spans 40..56
    _Float16*  AO1 = (_Float16*)(ws + 56 * MB);  // 8 MB
    _Float16*  AO2 = (_Float16*)(ws + 64 * MB);  // 8 MB

    cast_all<<<8192, 256, 0, stream>>>(x, Wq, Wk, Wv, Wo, xb, Wqb, Wkb, Wvb, Wof);

    qkv_gemm<<<dim3(24, 32), 256, 0, stream>>>(xb, Wqb, Wkb, Wvb, bq, bk, bv, Qb, Kb, VtH);

    den8<<<dim3(S_LEN / 64, S_LEN / 128, 2), 512, 0, stream>>>(Qb, Kb, rd);

    attn8<<<dim3((S_LEN / 128) * 2, NH / 2, 2), 512, 0, stream>>>(Qb, Kb, VtH, rd, AO1, AO2);

    gemm_out2<<<dim3(DIM / 64, MTOT / 128), 256, 0, stream>>>(AO1, AO2, Wof, bo, out);
}

// Round 9
// 260.281 us; speedup vs baseline: 1.2149x; 1.0228x over previous
//
#include <hip/hip_runtime.h>
#include <hip/hip_bf16.h>
#include <cstdint>
#include <cstddef>

// B=2, S=2048, D=1024, H=16, HD=64.  softmax over HEAD axis.
// v16: v15 minus s_setprio in attn8. v15 decomposition: C_EXP fold worked
//   (VALUBusy 30->24) but setprio regressed dur 71.5->78 -- attn8's 8 waves
//   are barrier-lockstep (m190 regime: setprio harmful), not independent
//   (m191 regime). Drop setprio permanently; keep the fold.
//   Structure otherwise v11-exact (best: 256.2us).

typedef __bf16 bf16x8 __attribute__((ext_vector_type(8)));
typedef __bf16 bf16x4 __attribute__((ext_vector_type(4)));
typedef _Float16 f16x2 __attribute__((ext_vector_type(2)));
typedef _Float16 f16x4 __attribute__((ext_vector_type(4)));
typedef _Float16 f16x8 __attribute__((ext_vector_type(8)));
typedef float floatx4 __attribute__((ext_vector_type(4)));

#define S_LEN 2048
#define DIM 1024
#define NH 16
#define HD 64
#define MTOT 4096  // B * S
#define C_EXP 0.1803368801111244f  // log2(e)/8

__device__ __forceinline__ float fast_exp2(float x) { return __builtin_amdgcn_exp2f(x); }

__device__ __forceinline__ f16x2 pk_cvt(float a, float b) {
    return __builtin_bit_cast(f16x2, __builtin_amdgcn_cvt_pkrtz(a, b));
}

__device__ __forceinline__ void g2l16(const void* g, void* l) {
    __builtin_amdgcn_global_load_lds(
        (const __attribute__((address_space(1))) void*)g,
        (__attribute__((address_space(3))) void*)l, 16, 0, 0);
}

// ---------------- fused cast: x -> bf16, Wq/Wk/Wv -> bf16, Wo -> f16 ----------------
__global__ void cast_all(const float* __restrict__ x,
                         const float* __restrict__ w0, const float* __restrict__ w1,
                         const float* __restrict__ w2, const float* __restrict__ w3,
                         __bf16* __restrict__ xb,
                         __bf16* __restrict__ o0, __bf16* __restrict__ o1,
                         __bf16* __restrict__ o2, _Float16* __restrict__ o3) {
    int bid = blockIdx.x;
    if (bid < 4096) {
        int i = (bid * 256 + threadIdx.x) * 4;
        float4 v = *(const float4*)&x[i];
        bf16x4 o;
        o.x = (__bf16)v.x; o.y = (__bf16)v.y; o.z = (__bf16)v.z; o.w = (__bf16)v.w;
        *(bf16x4*)&xb[i] = o;
        return;
    }
    bid -= 4096;
    int wi = bid >> 10;
    int i = ((bid & 1023) * 256 + threadIdx.x) * 4;
    if (wi == 3) {
        float4 v = *(const float4*)&w3[i];
        f16x4 o;
        o[0] = (_Float16)v.x; o[1] = (_Float16)v.y; o[2] = (_Float16)v.z; o[3] = (_Float16)v.w;
        *(f16x4*)&o3[i] = o;
        return;
    }
    const float* s = (wi == 0) ? w0 : (wi == 1) ? w1 : w2;
    __bf16* d = (wi == 0) ? o0 : (wi == 1) ? o1 : o2;
    float4 v = *(const float4*)&s[i];
    bf16x4 o;
    o.x = (__bf16)v.x; o.y = (__bf16)v.y; o.z = (__bf16)v.z; o.w = (__bf16)v.w;
    *(bf16x4*)&d[i] = o;
}

// ---------------- fused QKV projection GEMM (m97 structure) ----------------
// Qo epilogue is pre-scaled by C_EXP so den8/attn8 can exp2 the MFMA output directly.
__global__ __launch_bounds__(256, 2) void qkv_gemm(const __bf16* __restrict__ A,
                                                   const __bf16* __restrict__ Wq,
                                                   const __bf16* __restrict__ Wk,
                                                   const __bf16* __restrict__ Wv,
                                                   const float* __restrict__ bq,
                                                   const float* __restrict__ bk,
                                                   const float* __restrict__ bv,
                                                   __bf16* __restrict__ Qo,
                                                   __bf16* __restrict__ Ko,
                                                   _Float16* __restrict__ Vt) {
    const int tng = blockIdx.x * 128, tm = blockIdx.y * 128;
    const int wsel = tng >> 10, tn = tng & 1023;
    const __bf16* W = (wsel == 0) ? Wq : (wsel == 1) ? Wk : Wv;
    const float* bias = (wsel == 0) ? bq : (wsel == 1) ? bk : bv;
    __shared__ __bf16 As[128 * 32];
    __shared__ __bf16 Bs[128 * 32];
    const int tid = threadIdx.x, wid = tid >> 6, lane = tid & 63;
    const int l15 = lane & 15, quad = lane >> 4;
    const int wm = (wid >> 1) * 64, wn = (wid & 1) * 64;
    floatx4 acc[4][4] = {};
    for (int k0 = 0; k0 < DIM; k0 += 32) {
        __syncthreads();
#pragma unroll
        for (int i = 0; i < 2; ++i) {
            int slot = i * 256 + tid;
            int r = slot >> 2, c8 = (slot & 3) * 8;
            g2l16(&A[(size_t)(tm + r) * DIM + k0 + c8], &As[slot * 8]);
            g2l16(&W[(size_t)(tn + r) * DIM + k0 + c8], &Bs[slot * 8]);
        }
        __syncthreads();
        bf16x8 af[4], bf[4];
#pragma unroll
        for (int t = 0; t < 4; ++t) {
            af[t] = *(const bf16x8*)&As[(wm + t * 16 + l15) * 32 + quad * 8];
            bf[t] = *(const bf16x8*)&Bs[(wn + t * 16 + l15) * 32 + quad * 8];
        }
#pragma unroll
        for (int im = 0; im < 4; ++im)
#pragma unroll
            for (int in = 0; in < 4; ++in)
                acc[im][in] = __builtin_amdgcn_mfma_f32_16x16x32_bf16(af[im], bf[in], acc[im][in], 0, 0, 0);
    }
    if (wsel < 2) {
        __bf16* O = wsel ? Ko : Qo;
        const float qs = (wsel == 0) ? C_EXP : 1.0f;  // fold log2(e)/8 into Q
#pragma unroll
        for (int im = 0; im < 4; ++im)
#pragma unroll
            for (int in = 0; in < 4; ++in)
#pragma unroll
                for (int r = 0; r < 4; ++r) {
                    int row = tm + wm + im * 16 + quad * 4 + r;
                    int col = tn + wn + in * 16 + l15;
                    O[(size_t)row * DIM + col] = (__bf16)((acc[im][in][r] + bias[col]) * qs);
                }
    } else {
#pragma unroll
        for (int im = 0; im < 4; ++im)
#pragma unroll
            for (int in = 0; in < 4; ++in) {
                int cv = tn + wn + in * 16 + l15;
                int row4 = tm + wm + im * 16 + quad * 4;
                float bv_ = bias[cv];
                f16x4 o;
#pragma unroll
                for (int r = 0; r < 4; ++r) o[r] = (_Float16)(acc[im][in][r] + bv_);
                *(f16x4*)&Vt[(size_t)cv * MTOT + row4] = o;
            }
    }
}

// ---------------- pass 1: rd = 1/sum_h exp2(s')  (f16 out), 8-wave blocks ----------------
// Q is pre-scaled by C_EXP, so exp2 applies directly to the MFMA output.
__global__ __launch_bounds__(512, 8) void den8(const __bf16* __restrict__ Q,
                                               const __bf16* __restrict__ Km,
                                               _Float16* __restrict__ rd) {
    const int kt = blockIdx.x * 64, qt = blockIdx.y * 128, b = blockIdx.z;
    __shared__ __bf16 Ks[2][2 * 2 * 64 * 32];  // 2 bufs x 16 KB
    const int tid = threadIdx.x, wid = tid >> 6, lane = tid & 63;
    const int l15 = lane & 15, quad = lane >> 4;
    const int kswz = ((lane >> 1) & 3) << 3;  // element offset XOR for reads
    const int wq = wid * 16;
    floatx4 dsum[4] = {};
    const size_t qrow = (size_t)(b * S_LEN + qt + wq + l15) * DIM;
    const size_t kbase = (size_t)(b * S_LEN + kt) * DIM;

#pragma unroll
    for (int i = 0; i < 2; ++i) {
        int slot = i * 512 + tid;
        int hs = slot >> 9, rem = slot & 511;
        int p = rem >> 8, rem2 = rem & 255;
        int r = rem2 >> 2;
        int c8 = (((rem2 & 3) ^ ((rem2 >> 3) & 3)) * 8);  // pre-swizzled global slot
        g2l16(&Km[kbase + (size_t)r * DIM + hs * HD + p * 32 + c8], &Ks[0][slot * 8]);
    }
    for (int hh = 0; hh < 8; ++hh) {
        const int cur = hh & 1, nxt = cur ^ 1;
        __syncthreads();
        bf16x8 af[2][2];
#pragma unroll
        for (int hs = 0; hs < 2; ++hs) {
            af[hs][0] = *(const bf16x8*)&Q[qrow + (hh * 2 + hs) * HD + quad * 8];
            af[hs][1] = *(const bf16x8*)&Q[qrow + (hh * 2 + hs) * HD + 32 + quad * 8];
        }
        if (hh + 1 < 8) {
#pragma unroll
            for (int i = 0; i < 2; ++i) {
                int slot = i * 512 + tid;
                int hs = slot >> 9, rem = slot & 511;
                int p = rem >> 8, rem2 = rem & 255;
                int r = rem2 >> 2;
                int c8 = (((rem2 & 3) ^ ((rem2 >> 3) & 3)) * 8);
                g2l16(&Km[kbase + (size_t)r * DIM + ((hh + 1) * 2 + hs) * HD + p * 32 + c8],
                      &Ks[nxt][slot * 8]);
            }
        }
#pragma unroll
        for (int hs = 0; hs < 2; ++hs) {
#pragma unroll
            for (int n = 0; n < 4; ++n) {
                bf16x8 b0 = *(const bf16x8*)&Ks[cur][hs * 4096 + (n * 16 + l15) * 32 + ((quad * 8) ^ kswz)];
                bf16x8 b1 = *(const bf16x8*)&Ks[cur][hs * 4096 + 2048 + (n * 16 + l15) * 32 + ((quad * 8) ^ kswz)];
                floatx4 acc = {};
                acc = __builtin_amdgcn_mfma_f32_16x16x32_bf16(af[hs][0], b0, acc, 0, 0, 0);
                acc = __builtin_amdgcn_mfma_f32_16x16x32_bf16(af[hs][1], b1, acc, 0, 0, 0);
                floatx4 e;
#pragma unroll
                for (int r = 0; r < 4; ++r) e[r] = fast_exp2(acc[r]);
                dsum[n] += e;
            }
        }
    }
#pragma unroll
    for (int n = 0; n < 4; ++n)
#pragma unroll
        for (int r = 0; r < 4; ++r) {
            int q = qt + wq + quad * 4 + r;
            int k = kt + n * 16 + l15;
            rd[(size_t)(b * S_LEN + q) * S_LEN + k] = (_Float16)(1.0f / dsum[n][r]);
        }
}

// ---------------- pass 2: partial AO, TWO heads per block (v11 form, no setprio) ----------------
__global__ __launch_bounds__(512, 4) void attn8(const __bf16* __restrict__ Q,
                                                const __bf16* __restrict__ Km,
                                                const _Float16* __restrict__ Vt,
                                                const _Float16* __restrict__ rd,
                                                _Float16* __restrict__ AO1,
                                                _Float16* __restrict__ AO2) {
    const int qt = (blockIdx.x >> 1) * 128, ks = blockIdx.x & 1;
    const int h0 = blockIdx.y * 2, b = blockIdx.z;  // heads h0, h0+1
    __shared__ __bf16 Ks[2][2 * 2 * 64 * 32];   // [buf][head][panel][tok][32], 16KB/buf (swizzled)
    __shared__ _Float16 Vts[2][2 * 64 * 72];    // [buf][head][d][tok+pad], 18KB/buf
    const int tid = threadIdx.x, wid = tid >> 6, lane = tid & 63;
    const int l15 = lane & 15, quad = lane >> 4;
    const int kswz = ((lane >> 1) & 3) << 3;  // element offset XOR for reads
    const int wq = wid * 16;
    const size_t qrow = (size_t)(b * S_LEN + qt + wq + l15) * DIM + h0 * HD;
    bf16x8 qf[2][2];
    qf[0][0] = *(const bf16x8*)&Q[qrow + quad * 8];
    qf[0][1] = *(const bf16x8*)&Q[qrow + 32 + quad * 8];
    qf[1][0] = *(const bf16x8*)&Q[qrow + HD + quad * 8];
    qf[1][1] = *(const bf16x8*)&Q[qrow + HD + 32 + quad * 8];
    const _Float16* rdrow = &rd[(size_t)(b * S_LEN + qt + wq + l15) * S_LEN];
    floatx4 oacc[2][4] = {};
    const int kt0 = ks * (S_LEN / 2);
    const size_t kdim = (size_t)b * S_LEN * DIM;
    const int vr = tid >> 3, vc = (tid & 7) * 8;

#define STAGE_K(BUF, KT_)                                                            \
    {                                                                                \
        _Pragma("unroll")                                                            \
        for (int i = 0; i < 2; ++i) {                                                \
            int slot = i * 512 + tid;                                                \
            int hh = slot >> 9, rem = slot & 511;                                    \
            int p = rem >> 8, rem2 = rem & 255;                                      \
            int r = rem2 >> 2;                                                       \
            int c8 = (((rem2 & 3) ^ ((rem2 >> 3) & 3)) * 8);                         \
            g2l16(&Km[kdim + (size_t)((KT_) + r) * DIM + (h0 + hh) * HD + p * 32 + c8], \
                  &Ks[BUF][slot * 8]);                                               \
        }                                                                            \
    }

    // prologue: stage kt0 into buf 0
    {
        f16x8 v0 = *(const f16x8*)&Vt[(size_t)(h0 * HD + vr) * MTOT + b * S_LEN + kt0 + vc];
        f16x8 v1 = *(const f16x8*)&Vt[(size_t)((h0 + 1) * HD + vr) * MTOT + b * S_LEN + kt0 + vc];
        STAGE_K(0, kt0);
        *(f16x8*)&Vts[0][vr * 72 + vc] = v0;
        *(f16x8*)&Vts[0][4608 + vr * 72 + vc] = v1;
    }
    for (int it = 0; it < 16; ++it) {
        const int cur = it & 1, nxt = cur ^ 1;
        const int kt = kt0 + it * 64;
        __syncthreads();
        // rv for this iter -- SHARED by both heads (denominator is per (q,k))
        f16x4 rv[4];
#pragma unroll
        for (int mp = 0; mp < 4; ++mp)
            rv[mp] = *(const f16x4*)&rdrow[kt + mp * 16 + quad * 4];
        // issue next tile's loads (V kept in regs; committed to LDS after compute)
        f16x8 vt0, vt1;
        const bool has_next = (it + 1 < 16);
        if (has_next) {
            const int ktn = kt + 64;
            vt0 = *(const f16x8*)&Vt[(size_t)(h0 * HD + vr) * MTOT + b * S_LEN + ktn + vc];
            vt1 = *(const f16x8*)&Vt[(size_t)((h0 + 1) * HD + vr) * MTOT + b * S_LEN + ktn + vc];
            STAGE_K(nxt, ktn);
        }
        // compute current tile, both heads (Q pre-scaled: exp2 directly on s)
#pragma unroll
        for (int mp = 0; mp < 4; ++mp) {
            const int krow = (mp * 16 + l15) * 32 + ((quad * 8) ^ kswz);
            f16x4 pa[2];
#pragma unroll
            for (int hh = 0; hh < 2; ++hh) {
                bf16x8 kf0 = *(const bf16x8*)&Ks[cur][hh * 4096 + krow];
                bf16x8 kf1 = *(const bf16x8*)&Ks[cur][hh * 4096 + 2048 + krow];
                floatx4 s = {};
                s = __builtin_amdgcn_mfma_f32_16x16x32_bf16(kf0, qf[hh][0], s, 0, 0, 0);
                s = __builtin_amdgcn_mfma_f32_16x16x32_bf16(kf1, qf[hh][1], s, 0, 0, 0);
                f16x2 p01 = pk_cvt(fast_exp2(s[0]), fast_exp2(s[1]));
                f16x2 p23 = pk_cvt(fast_exp2(s[2]), fast_exp2(s[3]));
                f16x4 p = __builtin_shufflevector(p01, p23, 0, 1, 2, 3);
                pa[hh] = p * rv[mp];  // v_pk_mul_f16 x2
            }
#pragma unroll
            for (int hh = 0; hh < 2; ++hh)
#pragma unroll
                for (int n = 0; n < 4; ++n) {
                    f16x4 vb = *(const f16x4*)&Vts[cur][hh * 4608 + (n * 16 + l15) * 72 + mp * 16 + quad * 4];
                    oacc[hh][n] = __builtin_amdgcn_mfma_f32_16x16x16f16(pa[hh], vb, oacc[hh][n], 0, 0, 0);
                }
        }
        // commit next V tile to LDS (vmcnt wait lands here, after compute)
        if (has_next) {
            *(f16x8*)&Vts[nxt][vr * 72 + vc] = vt0;
            *(f16x8*)&Vts[nxt][4608 + vr * 72 + vc] = vt1;
        }
    }
#undef STAGE_K
    _Float16* AO = ks ? AO2 : AO1;
#pragma unroll
    for (int hh = 0; hh < 2; ++hh)
#pragma unroll
        for (int n = 0; n < 4; ++n)
#pragma unroll
            for (int r = 0; r < 4; ++r) {
                int row = qt + wq + quad * 4 + r;
                int col = (h0 + hh) * HD + n * 16 + l15;
                AO[(size_t)(b * S_LEN + row) * DIM + col] = (_Float16)oacc[hh][n][r];
            }
}

// ---------------- output projection: C = (AO1+AO2) @ Wo^T + bo ----------------
__global__ __launch_bounds__(256, 2) void gemm_out2(const _Float16* __restrict__ A1,
                                                    const _Float16* __restrict__ A2,
                                                    const _Float16* __restrict__ Bw,
                                                    const float* __restrict__ bias,
                                                    float* __restrict__ C) {
    const int tm = blockIdx.y * 128, tn = blockIdx.x * 64;
    __shared__ _Float16 As1[2 * 128 * 32];
    __shared__ _Float16 As2[2 * 128 * 32];
    __shared__ _Float16 Bs[2 * 64 * 32];
    const int tid = threadIdx.x, wid = tid >> 6, lane = tid & 63;
    const int l15 = lane & 15, quad = lane >> 4;
    const int wm = (wid >> 1) * 64, wn = (wid & 1) * 32;
    floatx4 acc[4][2] = {};
    for (int k0 = 0; k0 < DIM; k0 += 64) {
        __syncthreads();
#pragma unroll
        for (int i = 0; i < 4; ++i) {
            int slot = i * 256 + tid;
            int p = slot >> 9, rem = slot & 511;
            int r = rem >> 2, c8 = (rem & 3) * 8;
            size_t ga = (size_t)(tm + r) * DIM + k0 + p * 32 + c8;
            g2l16(&A1[ga], &As1[slot * 8]);
            g2l16(&A2[ga], &As2[slot * 8]);
        }
#pragma unroll
        for (int i = 0; i < 2; ++i) {
            int slot = i * 256 + tid;
            int p = slot >> 8, rem = slot & 255;
            int r = rem >> 2, c8 = (rem & 3) * 8;
            g2l16(&Bw[(size_t)(tn + r) * DIM + k0 + p * 32 + c8], &Bs[slot * 8]);
        }
        __syncthreads();
#pragma unroll
        for (int kc = 0; kc < 2; ++kc) {
            f16x8 af[4], bf[2];
#pragma unroll
            for (int t = 0; t < 4; ++t) {
                int off = kc * 4096 + (wm + t * 16 + l15) * 32 + quad * 8;
                f16x8 a1 = *(const f16x8*)&As1[off];
                f16x8 a2 = *(const f16x8*)&As2[off];
                af[t] = a1 + a2;
            }
#pragma unroll
            for (int t = 0; t < 2; ++t)
                bf[t] = *(const f16x8*)&Bs[kc * 2048 + (wn + t * 16 + l15) * 32 + quad * 8];
#pragma unroll
            for (int im = 0; im < 4; ++im)
#pragma unroll
                for (int in = 0; in < 2; ++in)
                    acc[im][in] = __builtin_amdgcn_mfma_f32_16x16x32_f16(af[im], bf[in], acc[im][in], 0, 0, 0);
        }
    }
#pragma unroll
    for (int im = 0; im < 4; ++im)
#pragma unroll
        for (int in = 0; in < 2; ++in)
#pragma unroll
            for (int r = 0; r < 4; ++r) {
                int row = tm + wm + im * 16 + quad * 4 + r;
                int col = tn + wn + in * 16 + l15;
                C[(size_t)row * DIM + col] = acc[im][in][r] + bias[col];
            }
}

extern "C" void kernel_launch(void* const* d_in, const int* in_sizes, int n_in,
                              void* d_out, int out_size, void* d_ws, size_t ws_size,
                              hipStream_t stream) {
    const float* x  = (const float*)d_in[0];
    const float* Wq = (const float*)d_in[1];
    const float* bq = (const float*)d_in[2];
    const float* Wk = (const float*)d_in[3];
    const float* bk = (const float*)d_in[4];
    const float* Wv = (const float*)d_in[5];
    const float* bv = (const float*)d_in[6];
    const float* Wo = (const float*)d_in[7];
    const float* bo = (const float*)d_in[8];
    float* out = (float*)d_out;

    char* ws = (char*)d_ws;
    const size_t MB = 1u << 20;
    __bf16*    xb  = (__bf16*)(ws);              // 8 MB
    __bf16*    Wqb = (__bf16*)(ws + 8 * MB);
    __bf16*    Wkb = (__bf16*)(ws + 10 * MB);
    __bf16*    Wvb = (__bf16*)(ws + 12 * MB);
    _Float16*  Wof = (_Float16*)(ws + 14 * MB);
    __bf16*    Qb  = (__bf16*)(ws + 16 * MB);    // 8 MB
    __bf16*    Kb  = (__bf16*)(ws + 24 * MB);    // 8 MB
    _Float16*  VtH = (_Float16*)(ws + 32 * MB);  // 8 MB
    _Float16*  rd  = (_Float16*)(ws + 40 * MB);  // 16 MB (f16, B*S*S) spans 40..56
    _Float16*  AO1 = (_Float16*)(ws + 56 * MB);  // 8 MB
    _Float16*  AO2 = (_Float16*)(ws + 64 * MB);  // 8 MB

    cast_all<<<8192, 256, 0, stream>>>(x, Wq, Wk, Wv, Wo, xb, Wqb, Wkb, Wvb, Wof);

    qkv_gemm<<<dim3(24, 32), 256, 0, stream>>>(xb, Wqb, Wkb, Wvb, bq, bk, bv, Qb, Kb, VtH);

    den8<<<dim3(S_LEN / 64, S_LEN / 128, 2), 512, 0, stream>>>(Qb, Kb, rd);

    attn8<<<dim3((S_LEN / 128) * 2, NH / 2, 2), 512, 0, stream>>>(Qb, Kb, VtH, rd, AO1, AO2);

    gemm_out2<<<dim3(DIM / 64, MTOT / 128), 256, 0, stream>>>(AO1, AO2, Wof, bo, out);
}

// Round 10
// 256.468 us; speedup vs baseline: 1.2329x; 1.0149x over previous
//
#include <hip/hip_runtime.h>
#include <hip/hip_bf16.h>
#include <cstdint>
#include <cstddef>

// B=2, S=2048, D=1024, H=16, HD=64.  softmax over HEAD axis.
// v17: v11-exact numerics path (C_EXP fold REVERTED -- v15/v16 showed the
//   s*C_EXP multiplies were free filler hiding MFMA->exp latency; removing
//   them cost ~4us. setprio stays out: m190 lockstep regime, -2.6us.)
//   One new lever: rv (denominator) software pipeline in attn8 -- load
//   rv(it+1) with the next-tile K/V issues, consume rv_cur loaded a full
//   compute phase earlier (de-exposes ~200cyc L2 latency per iter).
//   +8 VGPR (112->120 of 128 budget). K slot-swizzle retained.

typedef __bf16 bf16x8 __attribute__((ext_vector_type(8)));
typedef __bf16 bf16x4 __attribute__((ext_vector_type(4)));
typedef _Float16 f16x2 __attribute__((ext_vector_type(2)));
typedef _Float16 f16x4 __attribute__((ext_vector_type(4)));
typedef _Float16 f16x8 __attribute__((ext_vector_type(8)));
typedef float floatx4 __attribute__((ext_vector_type(4)));

#define S_LEN 2048
#define DIM 1024
#define NH 16
#define HD 64
#define MTOT 4096  // B * S
#define C_EXP 0.1803368801111244f  // log2(e)/8

__device__ __forceinline__ float fast_exp2(float x) { return __builtin_amdgcn_exp2f(x); }

__device__ __forceinline__ f16x2 pk_cvt(float a, float b) {
    return __builtin_bit_cast(f16x2, __builtin_amdgcn_cvt_pkrtz(a, b));
}

__device__ __forceinline__ void g2l16(const void* g, void* l) {
    __builtin_amdgcn_global_load_lds(
        (const __attribute__((address_space(1))) void*)g,
        (__attribute__((address_space(3))) void*)l, 16, 0, 0);
}

// ---------------- fused cast: x -> bf16, Wq/Wk/Wv -> bf16, Wo -> f16 ----------------
__global__ void cast_all(const float* __restrict__ x,
                         const float* __restrict__ w0, const float* __restrict__ w1,
                         const float* __restrict__ w2, const float* __restrict__ w3,
                         __bf16* __restrict__ xb,
                         __bf16* __restrict__ o0, __bf16* __restrict__ o1,
                         __bf16* __restrict__ o2, _Float16* __restrict__ o3) {
    int bid = blockIdx.x;
    if (bid < 4096) {
        int i = (bid * 256 + threadIdx.x) * 4;
        float4 v = *(const float4*)&x[i];
        bf16x4 o;
        o.x = (__bf16)v.x; o.y = (__bf16)v.y; o.z = (__bf16)v.z; o.w = (__bf16)v.w;
        *(bf16x4*)&xb[i] = o;
        return;
    }
    bid -= 4096;
    int wi = bid >> 10;
    int i = ((bid & 1023) * 256 + threadIdx.x) * 4;
    if (wi == 3) {
        float4 v = *(const float4*)&w3[i];
        f16x4 o;
        o[0] = (_Float16)v.x; o[1] = (_Float16)v.y; o[2] = (_Float16)v.z; o[3] = (_Float16)v.w;
        *(f16x4*)&o3[i] = o;
        return;
    }
    const float* s = (wi == 0) ? w0 : (wi == 1) ? w1 : w2;
    __bf16* d = (wi == 0) ? o0 : (wi == 1) ? o1 : o2;
    float4 v = *(const float4*)&s[i];
    bf16x4 o;
    o.x = (__bf16)v.x; o.y = (__bf16)v.y; o.z = (__bf16)v.z; o.w = (__bf16)v.w;
    *(bf16x4*)&d[i] = o;
}

// ---------------- fused QKV projection GEMM (m97 structure) ----------------
__global__ __launch_bounds__(256, 2) void qkv_gemm(const __bf16* __restrict__ A,
                                                   const __bf16* __restrict__ Wq,
                                                   const __bf16* __restrict__ Wk,
                                                   const __bf16* __restrict__ Wv,
                                                   const float* __restrict__ bq,
                                                   const float* __restrict__ bk,
                                                   const float* __restrict__ bv,
                                                   __bf16* __restrict__ Qo,
                                                   __bf16* __restrict__ Ko,
                                                   _Float16* __restrict__ Vt) {
    const int tng = blockIdx.x * 128, tm = blockIdx.y * 128;
    const int wsel = tng >> 10, tn = tng & 1023;
    const __bf16* W = (wsel == 0) ? Wq : (wsel == 1) ? Wk : Wv;
    const float* bias = (wsel == 0) ? bq : (wsel == 1) ? bk : bv;
    __shared__ __bf16 As[128 * 32];
    __shared__ __bf16 Bs[128 * 32];
    const int tid = threadIdx.x, wid = tid >> 6, lane = tid & 63;
    const int l15 = lane & 15, quad = lane >> 4;
    const int wm = (wid >> 1) * 64, wn = (wid & 1) * 64;
    floatx4 acc[4][4] = {};
    for (int k0 = 0; k0 < DIM; k0 += 32) {
        __syncthreads();
#pragma unroll
        for (int i = 0; i < 2; ++i) {
            int slot = i * 256 + tid;
            int r = slot >> 2, c8 = (slot & 3) * 8;
            g2l16(&A[(size_t)(tm + r) * DIM + k0 + c8], &As[slot * 8]);
            g2l16(&W[(size_t)(tn + r) * DIM + k0 + c8], &Bs[slot * 8]);
        }
        __syncthreads();
        bf16x8 af[4], bf[4];
#pragma unroll
        for (int t = 0; t < 4; ++t) {
            af[t] = *(const bf16x8*)&As[(wm + t * 16 + l15) * 32 + quad * 8];
            bf[t] = *(const bf16x8*)&Bs[(wn + t * 16 + l15) * 32 + quad * 8];
        }
#pragma unroll
        for (int im = 0; im < 4; ++im)
#pragma unroll
            for (int in = 0; in < 4; ++in)
                acc[im][in] = __builtin_amdgcn_mfma_f32_16x16x32_bf16(af[im], bf[in], acc[im][in], 0, 0, 0);
    }
    if (wsel < 2) {
        __bf16* O = wsel ? Ko : Qo;
#pragma unroll
        for (int im = 0; im < 4; ++im)
#pragma unroll
            for (int in = 0; in < 4; ++in)
#pragma unroll
                for (int r = 0; r < 4; ++r) {
                    int row = tm + wm + im * 16 + quad * 4 + r;
                    int col = tn + wn + in * 16 + l15;
                    O[(size_t)row * DIM + col] = (__bf16)(acc[im][in][r] + bias[col]);
                }
    } else {
#pragma unroll
        for (int im = 0; im < 4; ++im)
#pragma unroll
            for (int in = 0; in < 4; ++in) {
                int cv = tn + wn + in * 16 + l15;
                int row4 = tm + wm + im * 16 + quad * 4;
                float bv_ = bias[cv];
                f16x4 o;
#pragma unroll
                for (int r = 0; r < 4; ++r) o[r] = (_Float16)(acc[im][in][r] + bv_);
                *(f16x4*)&Vt[(size_t)cv * MTOT + row4] = o;
            }
    }
}

// ---------------- pass 1: rd = 1/sum_h exp(s/8)  (f16 out), 8-wave blocks ----------------
__global__ __launch_bounds__(512, 8) void den8(const __bf16* __restrict__ Q,
                                               const __bf16* __restrict__ Km,
                                               _Float16* __restrict__ rd) {
    const int kt = blockIdx.x * 64, qt = blockIdx.y * 128, b = blockIdx.z;
    __shared__ __bf16 Ks[2][2 * 2 * 64 * 32];  // 2 bufs x 16 KB
    const int tid = threadIdx.x, wid = tid >> 6, lane = tid & 63;
    const int l15 = lane & 15, quad = lane >> 4;
    const int kswz = ((lane >> 1) & 3) << 3;  // element offset XOR for reads
    const int wq = wid * 16;
    floatx4 dsum[4] = {};
    const size_t qrow = (size_t)(b * S_LEN + qt + wq + l15) * DIM;
    const size_t kbase = (size_t)(b * S_LEN + kt) * DIM;

#pragma unroll
    for (int i = 0; i < 2; ++i) {
        int slot = i * 512 + tid;
        int hs = slot >> 9, rem = slot & 511;
        int p = rem >> 8, rem2 = rem & 255;
        int r = rem2 >> 2;
        int c8 = (((rem2 & 3) ^ ((rem2 >> 3) & 3)) * 8);  // pre-swizzled global slot
        g2l16(&Km[kbase + (size_t)r * DIM + hs * HD + p * 32 + c8], &Ks[0][slot * 8]);
    }
    for (int hh = 0; hh < 8; ++hh) {
        const int cur = hh & 1, nxt = cur ^ 1;
        __syncthreads();
        bf16x8 af[2][2];
#pragma unroll
        for (int hs = 0; hs < 2; ++hs) {
            af[hs][0] = *(const bf16x8*)&Q[qrow + (hh * 2 + hs) * HD + quad * 8];
            af[hs][1] = *(const bf16x8*)&Q[qrow + (hh * 2 + hs) * HD + 32 + quad * 8];
        }
        if (hh + 1 < 8) {
#pragma unroll
            for (int i = 0; i < 2; ++i) {
                int slot = i * 512 + tid;
                int hs = slot >> 9, rem = slot & 511;
                int p = rem >> 8, rem2 = rem & 255;
                int r = rem2 >> 2;
                int c8 = (((rem2 & 3) ^ ((rem2 >> 3) & 3)) * 8);
                g2l16(&Km[kbase + (size_t)r * DIM + ((hh + 1) * 2 + hs) * HD + p * 32 + c8],
                      &Ks[nxt][slot * 8]);
            }
        }
#pragma unroll
        for (int hs = 0; hs < 2; ++hs) {
#pragma unroll
            for (int n = 0; n < 4; ++n) {
                bf16x8 b0 = *(const bf16x8*)&Ks[cur][hs * 4096 + (n * 16 + l15) * 32 + ((quad * 8) ^ kswz)];
                bf16x8 b1 = *(const bf16x8*)&Ks[cur][hs * 4096 + 2048 + (n * 16 + l15) * 32 + ((quad * 8) ^ kswz)];
                floatx4 acc = {};
                acc = __builtin_amdgcn_mfma_f32_16x16x32_bf16(af[hs][0], b0, acc, 0, 0, 0);
                acc = __builtin_amdgcn_mfma_f32_16x16x32_bf16(af[hs][1], b1, acc, 0, 0, 0);
                floatx4 sc = acc * C_EXP;
                floatx4 e;
#pragma unroll
                for (int r = 0; r < 4; ++r) e[r] = fast_exp2(sc[r]);
                dsum[n] += e;
            }
        }
    }
#pragma unroll
    for (int n = 0; n < 4; ++n)
#pragma unroll
        for (int r = 0; r < 4; ++r) {
            int q = qt + wq + quad * 4 + r;
            int k = kt + n * 16 + l15;
            rd[(size_t)(b * S_LEN + q) * S_LEN + k] = (_Float16)(1.0f / dsum[n][r]);
        }
}

// ---------------- pass 2: partial AO, TWO heads per block, rv pipelined ----------------
__global__ __launch_bounds__(512, 4) void attn8(const __bf16* __restrict__ Q,
                                                const __bf16* __restrict__ Km,
                                                const _Float16* __restrict__ Vt,
                                                const _Float16* __restrict__ rd,
                                                _Float16* __restrict__ AO1,
                                                _Float16* __restrict__ AO2) {
    const int qt = (blockIdx.x >> 1) * 128, ks = blockIdx.x & 1;
    const int h0 = blockIdx.y * 2, b = blockIdx.z;  // heads h0, h0+1
    __shared__ __bf16 Ks[2][2 * 2 * 64 * 32];   // [buf][head][panel][tok][32], 16KB/buf (swizzled)
    __shared__ _Float16 Vts[2][2 * 64 * 72];    // [buf][head][d][tok+pad], 18KB/buf
    const int tid = threadIdx.x, wid = tid >> 6, lane = tid & 63;
    const int l15 = lane & 15, quad = lane >> 4;
    const int kswz = ((lane >> 1) & 3) << 3;  // element offset XOR for reads
    const int wq = wid * 16;
    const size_t qrow = (size_t)(b * S_LEN + qt + wq + l15) * DIM + h0 * HD;
    bf16x8 qf[2][2];
    qf[0][0] = *(const bf16x8*)&Q[qrow + quad * 8];
    qf[0][1] = *(const bf16x8*)&Q[qrow + 32 + quad * 8];
    qf[1][0] = *(const bf16x8*)&Q[qrow + HD + quad * 8];
    qf[1][1] = *(const bf16x8*)&Q[qrow + HD + 32 + quad * 8];
    const _Float16* rdrow = &rd[(size_t)(b * S_LEN + qt + wq + l15) * S_LEN];
    floatx4 oacc[2][4] = {};
    const int kt0 = ks * (S_LEN / 2);
    const size_t kdim = (size_t)b * S_LEN * DIM;
    const int vr = tid >> 3, vc = (tid & 7) * 8;

#define STAGE_K(BUF, KT_)                                                            \
    {                                                                                \
        _Pragma("unroll")                                                            \
        for (int i = 0; i < 2; ++i) {                                                \
            int slot = i * 512 + tid;                                                \
            int hh = slot >> 9, rem = slot & 511;                                    \
            int p = rem >> 8, rem2 = rem & 255;                                      \
            int r = rem2 >> 2;                                                       \
            int c8 = (((rem2 & 3) ^ ((rem2 >> 3) & 3)) * 8);                         \
            g2l16(&Km[kdim + (size_t)((KT_) + r) * DIM + (h0 + hh) * HD + p * 32 + c8], \
                  &Ks[BUF][slot * 8]);                                               \
        }                                                                            \
    }

    // prologue: rv for it=0 issued FIRST (longest latency cover), then K/V stage
    f16x4 rv_cur[4];
#pragma unroll
    for (int mp = 0; mp < 4; ++mp)
        rv_cur[mp] = *(const f16x4*)&rdrow[kt0 + mp * 16 + quad * 4];
    {
        f16x8 v0 = *(const f16x8*)&Vt[(size_t)(h0 * HD + vr) * MTOT + b * S_LEN + kt0 + vc];
        f16x8 v1 = *(const f16x8*)&Vt[(size_t)((h0 + 1) * HD + vr) * MTOT + b * S_LEN + kt0 + vc];
        STAGE_K(0, kt0);
        *(f16x8*)&Vts[0][vr * 72 + vc] = v0;
        *(f16x8*)&Vts[0][4608 + vr * 72 + vc] = v1;
    }
    for (int it = 0; it < 16; ++it) {
        const int cur = it & 1, nxt = cur ^ 1;
        const int kt = kt0 + it * 64;
        __syncthreads();
        // issue next tile's loads: V to regs, K via g2l, rv(it+1) to regs
        f16x8 vt0, vt1;
        f16x4 rv_nxt[4];
        const bool has_next = (it + 1 < 16);
        if (has_next) {
            const int ktn = kt + 64;
            vt0 = *(const f16x8*)&Vt[(size_t)(h0 * HD + vr) * MTOT + b * S_LEN + ktn + vc];
            vt1 = *(const f16x8*)&Vt[(size_t)((h0 + 1) * HD + vr) * MTOT + b * S_LEN + ktn + vc];
            STAGE_K(nxt, ktn);
#pragma unroll
            for (int mp = 0; mp < 4; ++mp)
                rv_nxt[mp] = *(const f16x4*)&rdrow[ktn + mp * 16 + quad * 4];
        }
        // compute current tile, both heads, using rv_cur (loaded a full phase ago)
#pragma unroll
        for (int mp = 0; mp < 4; ++mp) {
            const int krow = (mp * 16 + l15) * 32 + ((quad * 8) ^ kswz);
            f16x4 pa[2];
#pragma unroll
            for (int hh = 0; hh < 2; ++hh) {
                bf16x8 kf0 = *(const bf16x8*)&Ks[cur][hh * 4096 + krow];
                bf16x8 kf1 = *(const bf16x8*)&Ks[cur][hh * 4096 + 2048 + krow];
                floatx4 s = {};
                s = __builtin_amdgcn_mfma_f32_16x16x32_bf16(kf0, qf[hh][0], s, 0, 0, 0);
                s = __builtin_amdgcn_mfma_f32_16x16x32_bf16(kf1, qf[hh][1], s, 0, 0, 0);
                floatx4 sc = s * C_EXP;
                f16x2 p01 = pk_cvt(fast_exp2(sc[0]), fast_exp2(sc[1]));
                f16x2 p23 = pk_cvt(fast_exp2(sc[2]), fast_exp2(sc[3]));
                f16x4 p = __builtin_shufflevector(p01, p23, 0, 1, 2, 3);
                pa[hh] = p * rv_cur[mp];  // v_pk_mul_f16 x2
            }
#pragma unroll
            for (int hh = 0; hh < 2; ++hh)
#pragma unroll
                for (int n = 0; n < 4; ++n) {
                    f16x4 vb = *(const f16x4*)&Vts[cur][hh * 4608 + (n * 16 + l15) * 72 + mp * 16 + quad * 4];
                    oacc[hh][n] = __builtin_amdgcn_mfma_f32_16x16x16f16(pa[hh], vb, oacc[hh][n], 0, 0, 0);
                }
        }
        // commit next V tile to LDS; rotate rv
        if (has_next) {
            *(f16x8*)&Vts[nxt][vr * 72 + vc] = vt0;
            *(f16x8*)&Vts[nxt][4608 + vr * 72 + vc] = vt1;
#pragma unroll
            for (int mp = 0; mp < 4; ++mp) rv_cur[mp] = rv_nxt[mp];
        }
    }
#undef STAGE_K
    _Float16* AO = ks ? AO2 : AO1;
#pragma unroll
    for (int hh = 0; hh < 2; ++hh)
#pragma unroll
        for (int n = 0; n < 4; ++n)
#pragma unroll
            for (int r = 0; r < 4; ++r) {
                int row = qt + wq + quad * 4 + r;
                int col = (h0 + hh) * HD + n * 16 + l15;
                AO[(size_t)(b * S_LEN + row) * DIM + col] = (_Float16)oacc[hh][n][r];
            }
}

// ---------------- output projection: C = (AO1+AO2) @ Wo^T + bo ----------------
__global__ __launch_bounds__(256, 2) void gemm_out2(const _Float16* __restrict__ A1,
                                                    const _Float16* __restrict__ A2,
                                                    const _Float16* __restrict__ Bw,
                                                    const float* __restrict__ bias,
                                                    float* __restrict__ C) {
    const int tm = blockIdx.y * 128, tn = blockIdx.x * 64;
    __shared__ _Float16 As1[2 * 128 * 32];
    __shared__ _Float16 As2[2 * 128 * 32];
    __shared__ _Float16 Bs[2 * 64 * 32];
    const int tid = threadIdx.x, wid = tid >> 6, lane = tid & 63;
    const int l15 = lane & 15, quad = lane >> 4;
    const int wm = (wid >> 1) * 64, wn = (wid & 1) * 32;
    floatx4 acc[4][2] = {};
    for (int k0 = 0; k0 < DIM; k0 += 64) {
        __syncthreads();
#pragma unroll
        for (int i = 0; i < 4; ++i) {
            int slot = i * 256 + tid;
            int p = slot >> 9, rem = slot & 511;
            int r = rem >> 2, c8 = (rem & 3) * 8;
            size_t ga = (size_t)(tm + r) * DIM + k0 + p * 32 + c8;
            g2l16(&A1[ga], &As1[slot * 8]);
            g2l16(&A2[ga], &As2[slot * 8]);
        }
#pragma unroll
        for (int i = 0; i < 2; ++i) {
            int slot = i * 256 + tid;
            int p = slot >> 8, rem = slot & 255;
            int r = rem >> 2, c8 = (rem & 3) * 8;
            g2l16(&Bw[(size_t)(tn + r) * DIM + k0 + p * 32 + c8], &Bs[slot * 8]);
        }
        __syncthreads();
#pragma unroll
        for (int kc = 0; kc < 2; ++kc) {
            f16x8 af[4], bf[2];
#pragma unroll
            for (int t = 0; t < 4; ++t) {
                int off = kc * 4096 + (wm + t * 16 + l15) * 32 + quad * 8;
                f16x8 a1 = *(const f16x8*)&As1[off];
                f16x8 a2 = *(const f16x8*)&As2[off];
                af[t] = a1 + a2;
            }
#pragma unroll
            for (int t = 0; t < 2; ++t)
                bf[t] = *(const f16x8*)&Bs[kc * 2048 + (wn + t * 16 + l15) * 32 + quad * 8];
#pragma unroll
            for (int im = 0; im < 4; ++im)
#pragma unroll
                for (int in = 0; in < 2; ++in)
                    acc[im][in] = __builtin_amdgcn_mfma_f32_16x16x32_f16(af[im], bf[in], acc[im][in], 0, 0, 0);
        }
    }
#pragma unroll
    for (int im = 0; im < 4; ++im)
#pragma unroll
        for (int in = 0; in < 2; ++in)
#pragma unroll
            for (int r = 0; r < 4; ++r) {
                int row = tm + wm + im * 16 + quad * 4 + r;
                int col = tn + wn + in * 16 + l15;
                C[(size_t)row * DIM + col] = acc[im][in][r] + bias[col];
            }
}

extern "C" void kernel_launch(void* const* d_in, const int* in_sizes, int n_in,
                              void* d_out, int out_size, void* d_ws, size_t ws_size,
                              hipStream_t stream) {
    const float* x  = (const float*)d_in[0];
    const float* Wq = (const float*)d_in[1];
    const float* bq = (const float*)d_in[2];
    const float* Wk = (const float*)d_in[3];
    const float* bk = (const float*)d_in[4];
    const float* Wv = (const float*)d_in[5];
    const float* bv = (const float*)d_in[6];
    const float* Wo = (const float*)d_in[7];
    const float* bo = (const float*)d_in[8];
    float* out = (float*)d_out;

    char* ws = (char*)d_ws;
    const size_t MB = 1u << 20;
    __bf16*    xb  = (__bf16*)(ws);              // 8 MB
    __bf16*    Wqb = (__bf16*)(ws + 8 * MB);
    __bf16*    Wkb = (__bf16*)(ws + 10 * MB);
    __bf16*    Wvb = (__bf16*)(ws + 12 * MB);
    _Float16*  Wof = (_Float16*)(ws + 14 * MB);
    __bf16*    Qb  = (__bf16*)(ws + 16 * MB);    // 8 MB
    __bf16*    Kb  = (__bf16*)(ws + 24 * MB);    // 8 MB
    _Float16*  VtH = (_Float16*)(ws + 32 * MB);  // 8 MB
    _Float16*  rd  = (_Float16*)(ws + 40 * MB);  // 16 MB (f16, B*S*S) spans 40..56
    _Float16*  AO1 = (_Float16*)(ws + 56 * MB);  // 8 MB
    _Float16*  AO2 = (_Float16*)(ws + 64 * MB);  // 8 MB

    cast_all<<<8192, 256, 0, stream>>>(x, Wq, Wk, Wv, Wo, xb, Wqb, Wkb, Wvb, Wof);

    qkv_gemm<<<dim3(24, 32), 256, 0, stream>>>(xb, Wqb, Wkb, Wvb, bq, bk, bv, Qb, Kb, VtH);

    den8<<<dim3(S_LEN / 64, S_LEN / 128, 2), 512, 0, stream>>>(Qb, Kb, rd);

    attn8<<<dim3((S_LEN / 128) * 2, NH / 2, 2), 512, 0, stream>>>(Qb, Kb, VtH, rd, AO1, AO2);

    gemm_out2<<<dim3(DIM / 64, MTOT / 128), 256, 0, stream>>>(AO1, AO2, Wof, bo, out);
}